// Round 10
// baseline (1658.141 us; speedup 1.0000x reference)
//
#include <hip/hip_runtime.h>

#define NROWS 65536
#define SB 256  // stride of the main ws activation buffer

__device__ __forceinline__ float frelu(float v) { return fmaxf(v, 0.f); }

// ---------------- ws layout (floats, relative to weight region W) ----------------
#define OFF_WT1   0        // [168][128]  enc_w1^T
#define OFF_WT2   21504    // [128][256]  enc_w2^T
#define OFF_WT3   54272    // [256][256]  enc_w3^T
#define OFF_WTQ   119808   // [256][64]   q_w^T
#define OFF_WTD1  136192   // [64][256]   dec_w1^T
#define OFF_WTD2  152576   // [256][128]  dec_w2^T
#define OFF_WTD3  185344   // [128][256]  dec_w3^T (o>=165 zero-padded)
#define OFF_WAPE  218112   // [2][64][32][4] enc_res_wa packed
#define OFF_WBTE  234496   // [2][32][256]   enc_res_wb^T
#define OFF_WAPD  250880   // [2][64][32][4] dec_res_wa packed
#define OFF_WBTD  267264   // [2][32][256]   dec_res_wb^T
#define OFF_ETG   283648   // [4][512][64]  codebook row-major
#define OFF_EN2   414720   // [4][512]      ||e_k||^2
#define OFF_DSUM  416768   // [1]
#define PREP_N    416769

// ---------------- fused prep kernel ----------------
__global__ void prep_k(const float* __restrict__ ew1, const float* __restrict__ ew2,
                       const float* __restrict__ ew3, const float* __restrict__ qw,
                       const float* __restrict__ dw1, const float* __restrict__ dw2,
                       const float* __restrict__ dw3, const float* __restrict__ ewa,
                       const float* __restrict__ ewb, const float* __restrict__ dwa,
                       const float* __restrict__ dwb, const float* __restrict__ embeds,
                       float* __restrict__ W) {
  int idx = blockIdx.x * 256 + threadIdx.x;
  if (idx < 21504) {  // wT1 [168][128] <- ew1 [128][165]
    int k = idx >> 7, o = idx & 127;
    W[OFF_WT1 + idx] = (k < 165) ? ew1[o * 165 + k] : 0.f;
    return;
  }
  idx -= 21504;
  if (idx < 32768) {  // wT2 [128][256]
    int k = idx >> 8, o = idx & 255;
    W[OFF_WT2 + idx] = ew2[o * 128 + k];
    return;
  }
  idx -= 32768;
  if (idx < 65536) {  // wT3 [256][256]
    int k = idx >> 8, o = idx & 255;
    W[OFF_WT3 + idx] = ew3[o * 256 + k];
    return;
  }
  idx -= 65536;
  if (idx < 16384) {  // wTq [256][64]
    int k = idx >> 6, o = idx & 63;
    W[OFF_WTQ + idx] = qw[o * 256 + k];
    return;
  }
  idx -= 16384;
  if (idx < 16384) {  // wTd1 [64][256]
    int k = idx >> 8, o = idx & 255;
    W[OFF_WTD1 + idx] = dw1[o * 64 + k];
    return;
  }
  idx -= 16384;
  if (idx < 32768) {  // wTd2 [256][128]
    int k = idx >> 7, o = idx & 127;
    W[OFF_WTD2 + idx] = dw2[o * 256 + k];
    return;
  }
  idx -= 32768;
  if (idx < 32768) {  // wTd3 [128][256], pad o>=165
    int k = idx >> 8, o = idx & 255;
    W[OFF_WTD3 + idx] = (o < 165) ? dw3[o * 128 + k] : 0.f;
    return;
  }
  idx -= 32768;
  if (idx < 16384) {  // waPe
    int l = idx >> 13, rem = idx & 8191;
    int k4 = rem >> 7, rem2 = rem & 127, o = rem2 >> 2, kk = rem2 & 3;
    W[OFF_WAPE + idx] = ewa[l * 8192 + o * 256 + k4 * 4 + kk];
    return;
  }
  idx -= 16384;
  if (idx < 16384) {  // wbTe
    int l = idx >> 13, rem = idx & 8191;
    int k = rem >> 8, o = rem & 255;
    W[OFF_WBTE + idx] = ewb[l * 8192 + o * 32 + k];
    return;
  }
  idx -= 16384;
  if (idx < 16384) {  // waPd
    int l = idx >> 13, rem = idx & 8191;
    int k4 = rem >> 7, rem2 = rem & 127, o = rem2 >> 2, kk = rem2 & 3;
    W[OFF_WAPD + idx] = dwa[l * 8192 + o * 256 + k4 * 4 + kk];
    return;
  }
  idx -= 16384;
  if (idx < 16384) {  // wbTd
    int l = idx >> 13, rem = idx & 8191;
    int k = rem >> 8, o = rem & 255;
    W[OFF_WBTD + idx] = dwb[l * 8192 + o * 32 + k];
    return;
  }
  idx -= 16384;
  if (idx < 131072) {  // etg[l][k][d]
    int d = idx & 63, k = (idx >> 6) & 511, l = idx >> 15;
    W[OFF_ETG + idx] = embeds[(l * 64 + d) * 512 + k];
    return;
  }
  idx -= 131072;
  if (idx < 2048) {  // en2
    int l = idx >> 9, k = idx & 511;
    float s = 0.f;
    for (int d = 0; d < 64; ++d) {
      float e = embeds[(l * 64 + d) * 512 + k];
      s = fmaf(e, e, s);
    }
    W[OFF_EN2 + idx] = s;
    return;
  }
  idx -= 2048;
  if (idx == 0) W[OFF_DSUM] = 0.f;
}

// ---------------- conv2_k: LDS x-stage (only for misaligned 165-stride input) ----
template <int CIN, int CINP, int COUT, int CP, int INSTRIDE, int OUTSTRIDE, bool RELU_IN,
          bool RELU_OUT>
__global__ __launch_bounds__(256, 4) void conv2_k(const float* in, const float* __restrict__ wT,
                                                  const float* __restrict__ b, float* out) {
  constexpr int COUTP = 64 * CP;
  constexpr bool GUARD = (COUT != COUTP);
  typedef float vCP __attribute__((ext_vector_type(CP)));
  __shared__ float xs[32][CINP];
  const int tid = threadIdx.x, lane = tid & 63, wv = tid >> 6;
  const long row0 = (long)blockIdx.x * 32;

  for (int i = tid; i < 32 * CINP; i += 256) {
    const int r = i / CINP, c = i % CINP;
    float v = (CIN == CINP || c < CIN) ? in[(row0 + r) * (long)INSTRIDE + c] : 0.f;
    if (RELU_IN) v = frelu(v);
    xs[r][c] = v;
  }
  __syncthreads();

  float acc[8][CP];
#pragma unroll
  for (int i = 0; i < 8; ++i)
#pragma unroll
    for (int j = 0; j < CP; ++j) acc[i][j] = 0.f;

  const float* wbase = wT + lane * CP;
#pragma unroll 4
  for (int k0 = 0; k0 < CINP; k0 += 4) {
    vCP wk[4];
#pragma unroll
    for (int kk = 0; kk < 4; ++kk) wk[kk] = *(const vCP*)(wbase + (k0 + kk) * COUTP);
#pragma unroll
    for (int rj = 0; rj < 8; ++rj) {
      const float4 x = *(const float4*)(&xs[wv * 8 + rj][k0]);
#pragma unroll
      for (int j = 0; j < CP; ++j) {
        acc[rj][j] = fmaf(x.x, wk[0][j], acc[rj][j]);
        acc[rj][j] = fmaf(x.y, wk[1][j], acc[rj][j]);
        acc[rj][j] = fmaf(x.z, wk[2][j], acc[rj][j]);
        acc[rj][j] = fmaf(x.w, wk[3][j], acc[rj][j]);
      }
    }
  }

  float bias[CP];
#pragma unroll
  for (int j = 0; j < CP; ++j) {
    const int o = lane * CP + j;
    bias[j] = (!GUARD || o < COUT) ? b[o] : 0.f;
  }
#pragma unroll
  for (int rj = 0; rj < 8; ++rj) {
    const long rbase = (row0 + wv * 8 + rj) * (long)OUTSTRIDE;
    if constexpr (!GUARD) {
      vCP v;
#pragma unroll
      for (int j = 0; j < CP; ++j) {
        const float t = acc[rj][j] + bias[j];
        v[j] = RELU_OUT ? frelu(t) : t;
      }
      *(vCP*)(out + rbase + lane * CP) = v;
    } else {
#pragma unroll
      for (int j = 0; j < CP; ++j) {
        const int o = lane * CP + j;
        if (o < COUT) {
          const float t = acc[rj][j] + bias[j];
          out[rbase + o] = RELU_OUT ? frelu(t) : t;
        }
      }
    }
  }
}

// ---------------- conv4_k: no-LDS, half-wave row split, 32-lane output groups ----
// Pipe budget (per k0-step, R=16 rows/wave, CP outs/lane over 32 lanes):
// FMA = 32*CP insts; x-loads 8 insts x 2 lines; w-loads CP insts x 8 lines.
// CP=8: TA ~0.6x, LDS = 0 (vs conv2_k's TA 1.0 + LDS 1.5 -> 55% VALU cap).
// No barriers. In-place safe: stores data-depend on all loads via acc.
// og=lane&31 owns outputs og*CP..og*CP+CP-1; rh=lane>>5 picks row half.
template <int CIN, int COUT, int CP, int INSTRIDE, int OUTSTRIDE, bool RELU_IN, bool RELU_OUT>
__global__ __launch_bounds__(256, 2) void conv4_k(const float* __restrict__ in,
                                                  const float* __restrict__ wT,
                                                  const float* __restrict__ b,
                                                  float* __restrict__ out) {
  constexpr int COUTP = 32 * CP;  // wT row width (padded layouts match)
  constexpr bool GUARD = (COUT != COUTP);
  typedef float vCP __attribute__((ext_vector_type(CP)));
  const int tid = threadIdx.x, lane = tid & 63, wv = tid >> 6;
  const int og = lane & 31, rh = lane >> 5;
  const long rowW = (long)blockIdx.x * 64 + wv * 16 + rh * 8;  // this half's 8 rows

  float acc[8][CP];
#pragma unroll
  for (int i = 0; i < 8; ++i)
#pragma unroll
    for (int j = 0; j < CP; ++j) acc[i][j] = 0.f;

  const float* wbase = wT + og * CP;
  const float* xbase = in + rowW * (long)INSTRIDE;

#pragma unroll 2
  for (int k0 = 0; k0 < CIN; k0 += 4) {
    const vCP wk0 = *(const vCP*)(wbase + (long)(k0 + 0) * COUTP);
    const vCP wk1 = *(const vCP*)(wbase + (long)(k0 + 1) * COUTP);
    const vCP wk2 = *(const vCP*)(wbase + (long)(k0 + 2) * COUTP);
    const vCP wk3 = *(const vCP*)(wbase + (long)(k0 + 3) * COUTP);
#pragma unroll
    for (int rj = 0; rj < 8; ++rj) {
      float4 x = *(const float4*)(xbase + (long)rj * INSTRIDE + k0);
      if (RELU_IN) {
        x.x = frelu(x.x);
        x.y = frelu(x.y);
        x.z = frelu(x.z);
        x.w = frelu(x.w);
      }
#pragma unroll
      for (int j = 0; j < CP; ++j) {
        acc[rj][j] = fmaf(x.x, wk0[j], acc[rj][j]);
        acc[rj][j] = fmaf(x.y, wk1[j], acc[rj][j]);
        acc[rj][j] = fmaf(x.z, wk2[j], acc[rj][j]);
        acc[rj][j] = fmaf(x.w, wk3[j], acc[rj][j]);
      }
    }
  }

  float bias[CP];
#pragma unroll
  for (int j = 0; j < CP; ++j) {
    const int o = og * CP + j;
    bias[j] = (!GUARD || o < COUT) ? b[o] : 0.f;
  }
#pragma unroll
  for (int rj = 0; rj < 8; ++rj) {
    const long rbase = (rowW + rj) * (long)OUTSTRIDE;
    if constexpr (!GUARD) {
      vCP v;
#pragma unroll
      for (int j = 0; j < CP; ++j) {
        const float t = acc[rj][j] + bias[j];
        v[j] = RELU_OUT ? frelu(t) : t;
      }
      *(vCP*)(out + rbase + og * CP) = v;
    } else {
#pragma unroll
      for (int j = 0; j < CP; ++j) {
        const int o = og * CP + j;
        if (o < COUT) {
          const float t = acc[rj][j] + bias[j];
          out[rbase + o] = RELU_OUT ? frelu(t) : t;
        }
      }
    }
  }
}

// ---------------- fused ResBlock PAIR, weights staged in LDS (proven R6) ----------------
__global__ __launch_bounds__(512, 4) void resblock_pair_k(
    float* xbuf, const float* __restrict__ waP, const float* __restrict__ ba,
    const float* __restrict__ wbT, const float* __restrict__ bb) {
  __shared__ float wls[8192];
  __shared__ float ts[64][36];
  const int tid = threadIdx.x, lane = tid & 63, wv = tid >> 6;
  const long row0 = (long)blockIdx.x * 64;
  const int o32 = lane & 31, rh = lane >> 5;

  for (int li = 0; li < 2; ++li) {
    __syncthreads();
    for (int i = tid; i < 8192; i += 512) wls[i] = waP[li * 8192 + i];
    __syncthreads();

    {
      float a0 = 0.f, a1 = 0.f, a2 = 0.f, a3 = 0.f;
      const float* xrow = xbuf + (row0 + wv * 8 + rh * 4) * (long)SB;
#pragma unroll 4
      for (int k0 = 0; k0 < 256; k0 += 4) {
        const float4 wq = *(const float4*)(&wls[k0 * 32 + o32 * 4]);
        const float4 x0 = *(const float4*)(xrow + 0 * SB + k0);
        const float4 x1 = *(const float4*)(xrow + 1 * SB + k0);
        const float4 x2 = *(const float4*)(xrow + 2 * SB + k0);
        const float4 x3 = *(const float4*)(xrow + 3 * SB + k0);
        a0 = fmaf(frelu(x0.x), wq.x, a0);
        a0 = fmaf(frelu(x0.y), wq.y, a0);
        a0 = fmaf(frelu(x0.z), wq.z, a0);
        a0 = fmaf(frelu(x0.w), wq.w, a0);
        a1 = fmaf(frelu(x1.x), wq.x, a1);
        a1 = fmaf(frelu(x1.y), wq.y, a1);
        a1 = fmaf(frelu(x1.z), wq.z, a1);
        a1 = fmaf(frelu(x1.w), wq.w, a1);
        a2 = fmaf(frelu(x2.x), wq.x, a2);
        a2 = fmaf(frelu(x2.y), wq.y, a2);
        a2 = fmaf(frelu(x2.z), wq.z, a2);
        a2 = fmaf(frelu(x2.w), wq.w, a2);
        a3 = fmaf(frelu(x3.x), wq.x, a3);
        a3 = fmaf(frelu(x3.y), wq.y, a3);
        a3 = fmaf(frelu(x3.z), wq.z, a3);
        a3 = fmaf(frelu(x3.w), wq.w, a3);
      }
      const float bal = ba[li * 32 + o32];
      const int rB = wv * 8 + rh * 4;
      ts[rB + 0][o32] = frelu(a0 + bal);
      ts[rB + 1][o32] = frelu(a1 + bal);
      ts[rB + 2][o32] = frelu(a2 + bal);
      ts[rB + 3][o32] = frelu(a3 + bal);
    }

    __syncthreads();
    for (int i = tid; i < 8192; i += 512) wls[i] = wbT[li * 8192 + i];
    __syncthreads();

    float acc2[8][4];
#pragma unroll
    for (int i = 0; i < 8; ++i)
#pragma unroll
      for (int j = 0; j < 4; ++j) acc2[i][j] = 0.f;

#pragma unroll
    for (int k0 = 0; k0 < 32; k0 += 4) {
      const float4 wk0 = *(const float4*)(&wls[(k0 + 0) * 256 + lane * 4]);
      const float4 wk1 = *(const float4*)(&wls[(k0 + 1) * 256 + lane * 4]);
      const float4 wk2 = *(const float4*)(&wls[(k0 + 2) * 256 + lane * 4]);
      const float4 wk3 = *(const float4*)(&wls[(k0 + 3) * 256 + lane * 4]);
#pragma unroll
      for (int rj = 0; rj < 8; ++rj) {
        const float4 t4 = *(const float4*)(&ts[wv * 8 + rj][k0]);
        acc2[rj][0] = fmaf(t4.x, wk0.x, acc2[rj][0]);
        acc2[rj][1] = fmaf(t4.x, wk0.y, acc2[rj][1]);
        acc2[rj][2] = fmaf(t4.x, wk0.z, acc2[rj][2]);
        acc2[rj][3] = fmaf(t4.x, wk0.w, acc2[rj][3]);
        acc2[rj][0] = fmaf(t4.y, wk1.x, acc2[rj][0]);
        acc2[rj][1] = fmaf(t4.y, wk1.y, acc2[rj][1]);
        acc2[rj][2] = fmaf(t4.y, wk1.z, acc2[rj][2]);
        acc2[rj][3] = fmaf(t4.y, wk1.w, acc2[rj][3]);
        acc2[rj][0] = fmaf(t4.z, wk2.x, acc2[rj][0]);
        acc2[rj][1] = fmaf(t4.z, wk2.y, acc2[rj][1]);
        acc2[rj][2] = fmaf(t4.z, wk2.z, acc2[rj][2]);
        acc2[rj][3] = fmaf(t4.z, wk2.w, acc2[rj][3]);
        acc2[rj][0] = fmaf(t4.w, wk3.x, acc2[rj][0]);
        acc2[rj][1] = fmaf(t4.w, wk3.y, acc2[rj][1]);
        acc2[rj][2] = fmaf(t4.w, wk3.z, acc2[rj][2]);
        acc2[rj][3] = fmaf(t4.w, wk3.w, acc2[rj][3]);
      }
    }
    const float4 bbv = *(const float4*)(bb + li * 256 + lane * 4);
#pragma unroll
    for (int rj = 0; rj < 8; ++rj) {
      float* xp = xbuf + (row0 + wv * 8 + rj) * (long)SB + lane * 4;
      const float4 xv = *(const float4*)xp;
      float4 nv;
      nv.x = xv.x + acc2[rj][0] + bbv.x;
      nv.y = xv.y + acc2[rj][1] + bbv.y;
      nv.z = xv.z + acc2[rj][2] + bbv.z;
      nv.w = xv.w + acc2[rj][3] + bbv.w;
      *(float4*)xp = nv;
    }
  }
}

// ---------------- residual VQ: 16 rows/wave, 8 codes/lane, minw=1 (VGPR cap 256) ----
// R9's shape was right but __launch_bounds__(256,2) capped VGPR at 128 (empirical
// cap = 256/minw across R6/R7/R9) -> acc[16][8]=128 spilled (WRITE 1.4 GB).
// minw=1 -> cap 256, acc fits, 2 waves/SIMD, pipes: LDS 0.75x, TA 0.5x.
__global__ __launch_bounds__(256, 1) void vq_k(float* buf, const float* __restrict__ embeds,
                                               const float* __restrict__ en2,
                                               const float* __restrict__ etg,
                                               float* __restrict__ dsum) {
  __shared__ float resL[64][68];
  const int tid = threadIdx.x;
  const int lane = tid & 63;
  const int wv = tid >> 6;
  const long row0 = (long)blockIdx.x * 64;

#pragma unroll
  for (int rj = 0; rj < 16; ++rj) {
    const int r = wv * 16 + rj;
    resL[r][lane] = buf[(row0 + r) * (long)SB + lane];
  }

  float dloc = 0.f;

  for (int l = 0; l < 4; ++l) {
    float best[16];
    int bk[16];
#pragma unroll
    for (int i = 0; i < 16; ++i) {
      best[i] = 3.4e38f;
      bk[i] = 0;
    }

    float acc[16][8];
#pragma unroll
    for (int i = 0; i < 16; ++i)
#pragma unroll
      for (int j = 0; j < 8; ++j) acc[i][j] = 0.f;

    const float* eb0 = embeds + ((long)l << 15) + lane * 4;  // kc=0 chunk
    const float* eb1 = eb0 + 256;                            // kc=1 chunk

#pragma unroll 2
    for (int dq = 0; dq < 16; ++dq) {
      const float4 ea0 = *(const float4*)(eb0 + ((dq * 4 + 0) << 9));
      const float4 ea1 = *(const float4*)(eb0 + ((dq * 4 + 1) << 9));
      const float4 ea2 = *(const float4*)(eb0 + ((dq * 4 + 2) << 9));
      const float4 ea3 = *(const float4*)(eb0 + ((dq * 4 + 3) << 9));
      const float4 eb0v = *(const float4*)(eb1 + ((dq * 4 + 0) << 9));
      const float4 eb1v = *(const float4*)(eb1 + ((dq * 4 + 1) << 9));
      const float4 eb2v = *(const float4*)(eb1 + ((dq * 4 + 2) << 9));
      const float4 eb3v = *(const float4*)(eb1 + ((dq * 4 + 3) << 9));
#pragma unroll
      for (int rj = 0; rj < 16; ++rj) {
        const float4 x = *(const float4*)(&resL[wv * 16 + rj][dq * 4]);
        acc[rj][0] = fmaf(x.x, ea0.x, acc[rj][0]);
        acc[rj][1] = fmaf(x.x, ea0.y, acc[rj][1]);
        acc[rj][2] = fmaf(x.x, ea0.z, acc[rj][2]);
        acc[rj][3] = fmaf(x.x, ea0.w, acc[rj][3]);
        acc[rj][4] = fmaf(x.x, eb0v.x, acc[rj][4]);
        acc[rj][5] = fmaf(x.x, eb0v.y, acc[rj][5]);
        acc[rj][6] = fmaf(x.x, eb0v.z, acc[rj][6]);
        acc[rj][7] = fmaf(x.x, eb0v.w, acc[rj][7]);
        acc[rj][0] = fmaf(x.y, ea1.x, acc[rj][0]);
        acc[rj][1] = fmaf(x.y, ea1.y, acc[rj][1]);
        acc[rj][2] = fmaf(x.y, ea1.z, acc[rj][2]);
        acc[rj][3] = fmaf(x.y, ea1.w, acc[rj][3]);
        acc[rj][4] = fmaf(x.y, eb1v.x, acc[rj][4]);
        acc[rj][5] = fmaf(x.y, eb1v.y, acc[rj][5]);
        acc[rj][6] = fmaf(x.y, eb1v.z, acc[rj][6]);
        acc[rj][7] = fmaf(x.y, eb1v.w, acc[rj][7]);
        acc[rj][0] = fmaf(x.z, ea2.x, acc[rj][0]);
        acc[rj][1] = fmaf(x.z, ea2.y, acc[rj][1]);
        acc[rj][2] = fmaf(x.z, ea2.z, acc[rj][2]);
        acc[rj][3] = fmaf(x.z, ea2.w, acc[rj][3]);
        acc[rj][4] = fmaf(x.z, eb2v.x, acc[rj][4]);
        acc[rj][5] = fmaf(x.z, eb2v.y, acc[rj][5]);
        acc[rj][6] = fmaf(x.z, eb2v.z, acc[rj][6]);
        acc[rj][7] = fmaf(x.z, eb2v.w, acc[rj][7]);
        acc[rj][0] = fmaf(x.w, ea3.x, acc[rj][0]);
        acc[rj][1] = fmaf(x.w, ea3.y, acc[rj][1]);
        acc[rj][2] = fmaf(x.w, ea3.z, acc[rj][2]);
        acc[rj][3] = fmaf(x.w, ea3.w, acc[rj][3]);
        acc[rj][4] = fmaf(x.w, eb3v.x, acc[rj][4]);
        acc[rj][5] = fmaf(x.w, eb3v.y, acc[rj][5]);
        acc[rj][6] = fmaf(x.w, eb3v.z, acc[rj][6]);
        acc[rj][7] = fmaf(x.w, eb3v.w, acc[rj][7]);
      }
    }

    const float4 e2a = *(const float4*)(en2 + l * 512 + lane * 4);
    const float4 e2b = *(const float4*)(en2 + l * 512 + 256 + lane * 4);
#pragma unroll
    for (int rj = 0; rj < 16; ++rj) {
      float s;
      s = fmaf(-2.f, acc[rj][0], e2a.x);
      if (s < best[rj]) { best[rj] = s; bk[rj] = lane * 4 + 0; }
      s = fmaf(-2.f, acc[rj][1], e2a.y);
      if (s < best[rj]) { best[rj] = s; bk[rj] = lane * 4 + 1; }
      s = fmaf(-2.f, acc[rj][2], e2a.z);
      if (s < best[rj]) { best[rj] = s; bk[rj] = lane * 4 + 2; }
      s = fmaf(-2.f, acc[rj][3], e2a.w);
      if (s < best[rj]) { best[rj] = s; bk[rj] = lane * 4 + 3; }
      s = fmaf(-2.f, acc[rj][4], e2b.x);
      if (s < best[rj]) { best[rj] = s; bk[rj] = 256 + lane * 4 + 0; }
      s = fmaf(-2.f, acc[rj][5], e2b.y);
      if (s < best[rj]) { best[rj] = s; bk[rj] = 256 + lane * 4 + 1; }
      s = fmaf(-2.f, acc[rj][6], e2b.z);
      if (s < best[rj]) { best[rj] = s; bk[rj] = 256 + lane * 4 + 2; }
      s = fmaf(-2.f, acc[rj][7], e2b.w);
      if (s < best[rj]) { best[rj] = s; bk[rj] = 256 + lane * 4 + 3; }
    }

#pragma unroll
    for (int rj = 0; rj < 16; ++rj) {
      float bv = best[rj];
      int bi = bk[rj];
#pragma unroll
      for (int m = 1; m < 64; m <<= 1) {
        const float ov = __shfl_xor(bv, m, 64);
        const int ok = __shfl_xor(bi, m, 64);
        if (ov < bv || (ov == bv && ok < bi)) {
          bv = ov;
          bi = ok;
        }
      }
      bk[rj] = bi;
    }

#pragma unroll
    for (int rj = 0; rj < 16; ++rj) {
      const int r = wv * 16 + rj;
      const float q = etg[((long)((l << 9) + bk[rj])) * 64 + lane];
      const float res = resL[r][lane];
      const float t = q - res;
      const float qst = res + t;
      dloc = fmaf(t, t, dloc);
      resL[r][lane] = res - qst;
      if (l == 0) buf[(row0 + r) * (long)SB + lane] = qst;
    }
  }

#pragma unroll
  for (int m = 1; m < 64; m <<= 1) dloc += __shfl_xor(dloc, m, 64);
  if (lane == 0) atomicAdd(dsum, dloc);
}

__global__ void finalize_k(const float* __restrict__ dsum, float* __restrict__ out) {
  if (threadIdx.x == 0 && blockIdx.x == 0)
    out[0] = *dsum * (1.0f / (4.0f * 65536.0f * 64.0f));
}

// ---------------- launch ----------------
extern "C" void kernel_launch(void* const* d_in, const int* in_sizes, int n_in, void* d_out,
                              int out_size, void* d_ws, size_t ws_size, hipStream_t stream) {
  (void)in_sizes; (void)n_in; (void)out_size; (void)ws_size;
  const float* x = (const float*)d_in[0];
  const float* enc_w1 = (const float*)d_in[1];
  const float* enc_b1 = (const float*)d_in[2];
  const float* enc_w2 = (const float*)d_in[3];
  const float* enc_b2 = (const float*)d_in[4];
  const float* enc_w3 = (const float*)d_in[5];
  const float* enc_b3 = (const float*)d_in[6];
  const float* enc_res_wa = (const float*)d_in[7];
  const float* enc_res_ba = (const float*)d_in[8];
  const float* enc_res_wb = (const float*)d_in[9];
  const float* enc_res_bb = (const float*)d_in[10];
  const float* q_w = (const float*)d_in[11];
  const float* q_b = (const float*)d_in[12];
  const float* embeds = (const float*)d_in[13];
  const float* dec_w1 = (const float*)d_in[14];
  const float* dec_b1 = (const float*)d_in[15];
  const float* dec_res_wa = (const float*)d_in[16];
  const float* dec_res_ba = (const float*)d_in[17];
  const float* dec_res_wb = (const float*)d_in[18];
  const float* dec_res_bb = (const float*)d_in[19];
  const float* dec_w2 = (const float*)d_in[20];
  const float* dec_b2 = (const float*)d_in[21];
  const float* dec_w3 = (const float*)d_in[22];
  const float* dec_b3 = (const float*)d_in[23];

  float* ws = (float*)d_ws;
  float* buf = ws;                          // [N][256]
  float* W = ws + (long)NROWS * SB;         // weight/codebook region

  float* dout = (float*)d_out;

  prep_k<<<(PREP_N + 255) / 256, 256, 0, stream>>>(enc_w1, enc_w2, enc_w3, q_w, dec_w1, dec_w2,
                                                   dec_w3, enc_res_wa, enc_res_wb, dec_res_wa,
                                                   dec_res_wb, embeds, W);

  const int GB = NROWS / 32;   // 2048 blocks (conv1)
  const int GR = NROWS / 64;   // 1024 blocks (conv4, resblock pairs, vq)

  // encoder
  conv2_k<165, 168, 128, 2, 165, SB, false, true><<<GB, 256, 0, stream>>>(x, W + OFF_WT1, enc_b1, buf);
  conv4_k<128, 256, 8, SB, SB, false, true><<<GR, 256, 0, stream>>>(buf, W + OFF_WT2, enc_b2, buf);
  conv4_k<256, 256, 8, SB, SB, false, false><<<GR, 256, 0, stream>>>(buf, W + OFF_WT3, enc_b3, buf);
  resblock_pair_k<<<GR, 512, 0, stream>>>(buf, W + OFF_WAPE, enc_res_ba, W + OFF_WBTE, enc_res_bb);
  conv4_k<256, 64, 2, SB, SB, true, false><<<GR, 256, 0, stream>>>(buf, W + OFF_WTQ, q_b, buf);

  // residual VQ
  vq_k<<<GR, 256, 0, stream>>>(buf, embeds, W + OFF_EN2, W + OFF_ETG, W + OFF_DSUM);

  // decoder
  conv4_k<64, 256, 8, SB, SB, false, false><<<GR, 256, 0, stream>>>(buf, W + OFF_WTD1, dec_b1, buf);
  resblock_pair_k<<<GR, 512, 0, stream>>>(buf, W + OFF_WAPD, dec_res_ba, W + OFF_WBTD, dec_res_bb);
  conv4_k<256, 128, 4, SB, SB, true, true><<<GR, 256, 0, stream>>>(buf, W + OFF_WTD2, dec_b2, buf);
  conv4_k<128, 165, 8, SB, 165, false, false><<<GR, 256, 0, stream>>>(buf, W + OFF_WTD3, dec_b3, dout);

  finalize_k<<<1, 64, 0, stream>>>(W + OFF_DSUM, dout + (long)NROWS * 165);
}

// Round 11
// 1221.827 us; speedup vs baseline: 1.3571x; 1.3571x over previous
//
#include <hip/hip_runtime.h>

#define NROWS 65536
#define SB 256  // stride of the main ws activation buffer

__device__ __forceinline__ float frelu(float v) { return fmaxf(v, 0.f); }

// ---------------- ws layout (floats, relative to weight region W) ----------------
#define OFF_WT1   0        // [168][128]  enc_w1^T
#define OFF_WT2   21504    // [128][256]  enc_w2^T
#define OFF_WT3   54272    // [256][256]  enc_w3^T
#define OFF_WTQ   119808   // [256][64]   q_w^T
#define OFF_WTD1  136192   // [64][256]   dec_w1^T
#define OFF_WTD2  152576   // [256][128]  dec_w2^T
#define OFF_WTD3  185344   // [128][256]  dec_w3^T (o>=165 zero-padded)
#define OFF_WAPE  218112   // [2][64][32][4] enc_res_wa packed
#define OFF_WBTE  234496   // [2][32][256]   enc_res_wb^T
#define OFF_WAPD  250880   // [2][64][32][4] dec_res_wa packed
#define OFF_WBTD  267264   // [2][32][256]   dec_res_wb^T
#define OFF_ETG   283648   // [4][512][64]  codebook row-major
#define OFF_EN2   414720   // [4][512]      ||e_k||^2
#define OFF_DSUM  416768   // [1]
#define PREP_N    416769

// ---------------- fused prep kernel ----------------
__global__ void prep_k(const float* __restrict__ ew1, const float* __restrict__ ew2,
                       const float* __restrict__ ew3, const float* __restrict__ qw,
                       const float* __restrict__ dw1, const float* __restrict__ dw2,
                       const float* __restrict__ dw3, const float* __restrict__ ewa,
                       const float* __restrict__ ewb, const float* __restrict__ dwa,
                       const float* __restrict__ dwb, const float* __restrict__ embeds,
                       float* __restrict__ W) {
  int idx = blockIdx.x * 256 + threadIdx.x;
  if (idx < 21504) {  // wT1 [168][128] <- ew1 [128][165]
    int k = idx >> 7, o = idx & 127;
    W[OFF_WT1 + idx] = (k < 165) ? ew1[o * 165 + k] : 0.f;
    return;
  }
  idx -= 21504;
  if (idx < 32768) {  // wT2 [128][256]
    int k = idx >> 8, o = idx & 255;
    W[OFF_WT2 + idx] = ew2[o * 128 + k];
    return;
  }
  idx -= 32768;
  if (idx < 65536) {  // wT3 [256][256]
    int k = idx >> 8, o = idx & 255;
    W[OFF_WT3 + idx] = ew3[o * 256 + k];
    return;
  }
  idx -= 65536;
  if (idx < 16384) {  // wTq [256][64]
    int k = idx >> 6, o = idx & 63;
    W[OFF_WTQ + idx] = qw[o * 256 + k];
    return;
  }
  idx -= 16384;
  if (idx < 16384) {  // wTd1 [64][256]
    int k = idx >> 8, o = idx & 255;
    W[OFF_WTD1 + idx] = dw1[o * 64 + k];
    return;
  }
  idx -= 16384;
  if (idx < 32768) {  // wTd2 [256][128]
    int k = idx >> 7, o = idx & 127;
    W[OFF_WTD2 + idx] = dw2[o * 256 + k];
    return;
  }
  idx -= 32768;
  if (idx < 32768) {  // wTd3 [128][256], pad o>=165
    int k = idx >> 8, o = idx & 255;
    W[OFF_WTD3 + idx] = (o < 165) ? dw3[o * 128 + k] : 0.f;
    return;
  }
  idx -= 32768;
  if (idx < 16384) {  // waPe
    int l = idx >> 13, rem = idx & 8191;
    int k4 = rem >> 7, rem2 = rem & 127, o = rem2 >> 2, kk = rem2 & 3;
    W[OFF_WAPE + idx] = ewa[l * 8192 + o * 256 + k4 * 4 + kk];
    return;
  }
  idx -= 16384;
  if (idx < 16384) {  // wbTe
    int l = idx >> 13, rem = idx & 8191;
    int k = rem >> 8, o = rem & 255;
    W[OFF_WBTE + idx] = ewb[l * 8192 + o * 32 + k];
    return;
  }
  idx -= 16384;
  if (idx < 16384) {  // waPd
    int l = idx >> 13, rem = idx & 8191;
    int k4 = rem >> 7, rem2 = rem & 127, o = rem2 >> 2, kk = rem2 & 3;
    W[OFF_WAPD + idx] = dwa[l * 8192 + o * 256 + k4 * 4 + kk];
    return;
  }
  idx -= 16384;
  if (idx < 16384) {  // wbTd
    int l = idx >> 13, rem = idx & 8191;
    int k = rem >> 8, o = rem & 255;
    W[OFF_WBTD + idx] = dwb[l * 8192 + o * 32 + k];
    return;
  }
  idx -= 16384;
  if (idx < 131072) {  // etg[l][k][d]
    int d = idx & 63, k = (idx >> 6) & 511, l = idx >> 15;
    W[OFF_ETG + idx] = embeds[(l * 64 + d) * 512 + k];
    return;
  }
  idx -= 131072;
  if (idx < 2048) {  // en2
    int l = idx >> 9, k = idx & 511;
    float s = 0.f;
    for (int d = 0; d < 64; ++d) {
      float e = embeds[(l * 64 + d) * 512 + k];
      s = fmaf(e, e, s);
    }
    W[OFF_EN2 + idx] = s;
    return;
  }
  idx -= 2048;
  if (idx == 0) W[OFF_DSUM] = 0.f;
}

// ---------------- conv2_k: R6 proven form (LDS x-stage, lane=output) ----------------
template <int CIN, int CINP, int COUT, int CP, int INSTRIDE, int OUTSTRIDE, bool RELU_IN,
          bool RELU_OUT>
__global__ __launch_bounds__(256, 4) void conv2_k(const float* in, const float* __restrict__ wT,
                                                  const float* __restrict__ b, float* out) {
  constexpr int COUTP = 64 * CP;
  constexpr bool GUARD = (COUT != COUTP);
  typedef float vCP __attribute__((ext_vector_type(CP)));
  __shared__ float xs[32][CINP];
  const int tid = threadIdx.x, lane = tid & 63, wv = tid >> 6;
  const long row0 = (long)blockIdx.x * 32;

  for (int i = tid; i < 32 * CINP; i += 256) {
    const int r = i / CINP, c = i % CINP;
    float v = (CIN == CINP || c < CIN) ? in[(row0 + r) * (long)INSTRIDE + c] : 0.f;
    if (RELU_IN) v = frelu(v);
    xs[r][c] = v;
  }
  __syncthreads();

  float acc[8][CP];
#pragma unroll
  for (int i = 0; i < 8; ++i)
#pragma unroll
    for (int j = 0; j < CP; ++j) acc[i][j] = 0.f;

  const float* wbase = wT + lane * CP;
#pragma unroll 4
  for (int k0 = 0; k0 < CINP; k0 += 4) {
    vCP wk[4];
#pragma unroll
    for (int kk = 0; kk < 4; ++kk) wk[kk] = *(const vCP*)(wbase + (k0 + kk) * COUTP);
#pragma unroll
    for (int rj = 0; rj < 8; ++rj) {
      const float4 x = *(const float4*)(&xs[wv * 8 + rj][k0]);
#pragma unroll
      for (int j = 0; j < CP; ++j) {
        acc[rj][j] = fmaf(x.x, wk[0][j], acc[rj][j]);
        acc[rj][j] = fmaf(x.y, wk[1][j], acc[rj][j]);
        acc[rj][j] = fmaf(x.z, wk[2][j], acc[rj][j]);
        acc[rj][j] = fmaf(x.w, wk[3][j], acc[rj][j]);
      }
    }
  }

  float bias[CP];
#pragma unroll
  for (int j = 0; j < CP; ++j) {
    const int o = lane * CP + j;
    bias[j] = (!GUARD || o < COUT) ? b[o] : 0.f;
  }
#pragma unroll
  for (int rj = 0; rj < 8; ++rj) {
    const long rbase = (row0 + wv * 8 + rj) * (long)OUTSTRIDE;
    if constexpr (!GUARD) {
      vCP v;
#pragma unroll
      for (int j = 0; j < CP; ++j) {
        const float t = acc[rj][j] + bias[j];
        v[j] = RELU_OUT ? frelu(t) : t;
      }
      *(vCP*)(out + rbase + lane * CP) = v;
    } else {
#pragma unroll
      for (int j = 0; j < CP; ++j) {
        const int o = lane * CP + j;
        if (o < COUT) {
          const float t = acc[rj][j] + bias[j];
          out[rbase + o] = RELU_OUT ? frelu(t) : t;
        }
      }
    }
  }
}

// ---------------- conv6_k: per-tile TRANSPOSED x (lane = row), scalar weights --------
// 64 rows/block, 512 threads (8 waves). xT staged in LDS [CIN][65] (pad -> both
// the transposed write and the per-k read are bank-conflict-free). lane = row;
// wave wv owns the 32-output tile o = wv*32..+31. Weight address is wave-uniform
// (wv via readfirstlane) -> compiler emits s_load on the SCALAR pipe: TA ~0,
// LDS = one ds_read_b32 per k shared by 32 FMA (ratio 0.375 vs conv2's 1.5).
// acc[32] keeps VGPR ~50 -> 16 waves/CU (LDS-limited 2 blocks). 3 barriers total:
// stage, acc->LDS-transpose, coalesced write-out. In-place safe (reads precede
// writes across barriers).
template <int CIN, int COUT, int COUTP, int INSTRIDE, int OUTSTRIDE, bool RELU_IN, bool RELU_OUT>
__global__ __launch_bounds__(512, 2) void conv6_k(const float* __restrict__ in,
                                                  const float* __restrict__ wT,
                                                  const float* __restrict__ b,
                                                  float* __restrict__ out) {
  constexpr int MAXD = (CIN > COUT) ? CIN : COUT;
  __shared__ float lds[MAXD * 65];
  const int tid = threadIdx.x;
  const int lane = tid & 63;
  const int wv = __builtin_amdgcn_readfirstlane(tid >> 6);
  const long row0 = (long)blockIdx.x * 64;

  // stage x transposed: lds[c*65 + r] = x[row0+r][c]
  constexpr int C4 = CIN / 4;
  for (int i = tid; i < 64 * C4; i += 512) {
    const int r = i / C4, c4 = i % C4;
    float4 v = *(const float4*)(in + (row0 + r) * (long)INSTRIDE + c4 * 4);
    if (RELU_IN) {
      v.x = frelu(v.x);
      v.y = frelu(v.y);
      v.z = frelu(v.z);
      v.w = frelu(v.w);
    }
    lds[(c4 * 4 + 0) * 65 + r] = v.x;
    lds[(c4 * 4 + 1) * 65 + r] = v.y;
    lds[(c4 * 4 + 2) * 65 + r] = v.z;
    lds[(c4 * 4 + 3) * 65 + r] = v.w;
  }
  __syncthreads();

  float acc[32];
#pragma unroll
  for (int j = 0; j < 32; ++j) acc[j] = 0.f;

  const float* wrow = wT + wv * 32;
#pragma unroll 2
  for (int k = 0; k < CIN; ++k) {
    const float xv = lds[k * 65 + lane];
    const float* wk = wrow + (long)k * COUTP;
#pragma unroll
    for (int j = 0; j < 32; ++j) acc[j] = fmaf(xv, wk[j], acc[j]);
  }

  const float* bb = b + wv * 32;
#pragma unroll
  for (int j = 0; j < 32; ++j) {
    float t = acc[j] + bb[j];
    acc[j] = RELU_OUT ? frelu(t) : t;
  }

  // transpose back through LDS, then coalesced global write
  __syncthreads();
#pragma unroll
  for (int j = 0; j < 32; ++j) lds[(wv * 32 + j) * 65 + lane] = acc[j];
  __syncthreads();

  constexpr int O4 = COUT / 4;
  for (int i = tid; i < 64 * O4; i += 512) {
    const int r = i / O4, c4 = i % O4;
    float4 v;
    v.x = lds[(c4 * 4 + 0) * 65 + r];
    v.y = lds[(c4 * 4 + 1) * 65 + r];
    v.z = lds[(c4 * 4 + 2) * 65 + r];
    v.w = lds[(c4 * 4 + 3) * 65 + r];
    *(float4*)(out + (row0 + r) * (long)OUTSTRIDE + c4 * 4) = v;
  }
}

// ---------------- fused ResBlock PAIR, weights staged in LDS (proven R6) ----------------
__global__ __launch_bounds__(512, 4) void resblock_pair_k(
    float* xbuf, const float* __restrict__ waP, const float* __restrict__ ba,
    const float* __restrict__ wbT, const float* __restrict__ bb) {
  __shared__ float wls[8192];
  __shared__ float ts[64][36];
  const int tid = threadIdx.x, lane = tid & 63, wv = tid >> 6;
  const long row0 = (long)blockIdx.x * 64;
  const int o32 = lane & 31, rh = lane >> 5;

  for (int li = 0; li < 2; ++li) {
    __syncthreads();
    for (int i = tid; i < 8192; i += 512) wls[i] = waP[li * 8192 + i];
    __syncthreads();

    {
      float a0 = 0.f, a1 = 0.f, a2 = 0.f, a3 = 0.f;
      const float* xrow = xbuf + (row0 + wv * 8 + rh * 4) * (long)SB;
#pragma unroll 4
      for (int k0 = 0; k0 < 256; k0 += 4) {
        const float4 wq = *(const float4*)(&wls[k0 * 32 + o32 * 4]);
        const float4 x0 = *(const float4*)(xrow + 0 * SB + k0);
        const float4 x1 = *(const float4*)(xrow + 1 * SB + k0);
        const float4 x2 = *(const float4*)(xrow + 2 * SB + k0);
        const float4 x3 = *(const float4*)(xrow + 3 * SB + k0);
        a0 = fmaf(frelu(x0.x), wq.x, a0);
        a0 = fmaf(frelu(x0.y), wq.y, a0);
        a0 = fmaf(frelu(x0.z), wq.z, a0);
        a0 = fmaf(frelu(x0.w), wq.w, a0);
        a1 = fmaf(frelu(x1.x), wq.x, a1);
        a1 = fmaf(frelu(x1.y), wq.y, a1);
        a1 = fmaf(frelu(x1.z), wq.z, a1);
        a1 = fmaf(frelu(x1.w), wq.w, a1);
        a2 = fmaf(frelu(x2.x), wq.x, a2);
        a2 = fmaf(frelu(x2.y), wq.y, a2);
        a2 = fmaf(frelu(x2.z), wq.z, a2);
        a2 = fmaf(frelu(x2.w), wq.w, a2);
        a3 = fmaf(frelu(x3.x), wq.x, a3);
        a3 = fmaf(frelu(x3.y), wq.y, a3);
        a3 = fmaf(frelu(x3.z), wq.z, a3);
        a3 = fmaf(frelu(x3.w), wq.w, a3);
      }
      const float bal = ba[li * 32 + o32];
      const int rB = wv * 8 + rh * 4;
      ts[rB + 0][o32] = frelu(a0 + bal);
      ts[rB + 1][o32] = frelu(a1 + bal);
      ts[rB + 2][o32] = frelu(a2 + bal);
      ts[rB + 3][o32] = frelu(a3 + bal);
    }

    __syncthreads();
    for (int i = tid; i < 8192; i += 512) wls[i] = wbT[li * 8192 + i];
    __syncthreads();

    float acc2[8][4];
#pragma unroll
    for (int i = 0; i < 8; ++i)
#pragma unroll
      for (int j = 0; j < 4; ++j) acc2[i][j] = 0.f;

#pragma unroll
    for (int k0 = 0; k0 < 32; k0 += 4) {
      const float4 wk0 = *(const float4*)(&wls[(k0 + 0) * 256 + lane * 4]);
      const float4 wk1 = *(const float4*)(&wls[(k0 + 1) * 256 + lane * 4]);
      const float4 wk2 = *(const float4*)(&wls[(k0 + 2) * 256 + lane * 4]);
      const float4 wk3 = *(const float4*)(&wls[(k0 + 3) * 256 + lane * 4]);
#pragma unroll
      for (int rj = 0; rj < 8; ++rj) {
        const float4 t4 = *(const float4*)(&ts[wv * 8 + rj][k0]);
        acc2[rj][0] = fmaf(t4.x, wk0.x, acc2[rj][0]);
        acc2[rj][1] = fmaf(t4.x, wk0.y, acc2[rj][1]);
        acc2[rj][2] = fmaf(t4.x, wk0.z, acc2[rj][2]);
        acc2[rj][3] = fmaf(t4.x, wk0.w, acc2[rj][3]);
        acc2[rj][0] = fmaf(t4.y, wk1.x, acc2[rj][0]);
        acc2[rj][1] = fmaf(t4.y, wk1.y, acc2[rj][1]);
        acc2[rj][2] = fmaf(t4.y, wk1.z, acc2[rj][2]);
        acc2[rj][3] = fmaf(t4.y, wk1.w, acc2[rj][3]);
        acc2[rj][0] = fmaf(t4.z, wk2.x, acc2[rj][0]);
        acc2[rj][1] = fmaf(t4.z, wk2.y, acc2[rj][1]);
        acc2[rj][2] = fmaf(t4.z, wk2.z, acc2[rj][2]);
        acc2[rj][3] = fmaf(t4.z, wk2.w, acc2[rj][3]);
        acc2[rj][0] = fmaf(t4.w, wk3.x, acc2[rj][0]);
        acc2[rj][1] = fmaf(t4.w, wk3.y, acc2[rj][1]);
        acc2[rj][2] = fmaf(t4.w, wk3.z, acc2[rj][2]);
        acc2[rj][3] = fmaf(t4.w, wk3.w, acc2[rj][3]);
      }
    }
    const float4 bbv = *(const float4*)(bb + li * 256 + lane * 4);
#pragma unroll
    for (int rj = 0; rj < 8; ++rj) {
      float* xp = xbuf + (row0 + wv * 8 + rj) * (long)SB + lane * 4;
      const float4 xv = *(const float4*)xp;
      float4 nv;
      nv.x = xv.x + acc2[rj][0] + bbv.x;
      nv.y = xv.y + acc2[rj][1] + bbv.y;
      nv.z = xv.z + acc2[rj][2] + bbv.z;
      nv.w = xv.w + acc2[rj][3] + bbv.w;
      *(float4*)xp = nv;
    }
  }
}

// ---------------- residual VQ (exact R6 form: 344 us proven) ----------------
__global__ __launch_bounds__(256, 4) void vq_k(float* buf, const float* __restrict__ embeds,
                                               const float* __restrict__ en2,
                                               const float* __restrict__ etg,
                                               float* __restrict__ dsum) {
  __shared__ float resL[32][68];
  const int tid = threadIdx.x;
  const int lane = tid & 63;
  const int wv = tid >> 6;
  const long row0 = (long)blockIdx.x * 32;

  for (int rj = 0; rj < 8; ++rj) {
    const int r = wv * 8 + rj;
    resL[r][lane] = buf[(row0 + r) * (long)SB + lane];
  }

  float dloc = 0.f;

  for (int l = 0; l < 4; ++l) {
    float best[8];
    int bk[8];
#pragma unroll
    for (int i = 0; i < 8; ++i) {
      best[i] = 3.4e38f;
      bk[i] = 0;
    }

    for (int kc = 0; kc < 2; ++kc) {
      float acc[8][4];
#pragma unroll
      for (int i = 0; i < 8; ++i)
#pragma unroll
        for (int j = 0; j < 4; ++j) acc[i][j] = 0.f;

      const float* eb = embeds + ((long)l << 15) + (kc << 8) + lane * 4;
#pragma unroll 2
      for (int dq = 0; dq < 16; ++dq) {
        float4 x4[8];
#pragma unroll
        for (int rj = 0; rj < 8; ++rj) x4[rj] = *(const float4*)(&resL[wv * 8 + rj][dq * 4]);
#pragma unroll
        for (int dd = 0; dd < 4; ++dd) {
          const float4 e4 = *(const float4*)(eb + ((dq * 4 + dd) << 9));
#pragma unroll
          for (int rj = 0; rj < 8; ++rj) {
            const float xv = dd == 0 ? x4[rj].x : dd == 1 ? x4[rj].y : dd == 2 ? x4[rj].z : x4[rj].w;
            acc[rj][0] = fmaf(xv, e4.x, acc[rj][0]);
            acc[rj][1] = fmaf(xv, e4.y, acc[rj][1]);
            acc[rj][2] = fmaf(xv, e4.z, acc[rj][2]);
            acc[rj][3] = fmaf(xv, e4.w, acc[rj][3]);
          }
        }
      }

      const float4 e2 = *(const float4*)(en2 + l * 512 + kc * 256 + lane * 4);
#pragma unroll
      for (int rj = 0; rj < 8; ++rj) {
#pragma unroll
        for (int j = 0; j < 4; ++j) {
          const float ev = j == 0 ? e2.x : j == 1 ? e2.y : j == 2 ? e2.z : e2.w;
          const float s = fmaf(-2.f, acc[rj][j], ev);
          const int k = kc * 256 + lane * 4 + j;
          if (s < best[rj]) {
            best[rj] = s;
            bk[rj] = k;
          }
        }
      }
    }

    // cross-lane first-min argmin
#pragma unroll
    for (int rj = 0; rj < 8; ++rj) {
      float bv = best[rj];
      int bi = bk[rj];
#pragma unroll
      for (int m = 1; m < 64; m <<= 1) {
        const float ov = __shfl_xor(bv, m, 64);
        const int ok = __shfl_xor(bi, m, 64);
        if (ov < bv || (ov == bv && ok < bi)) {
          bv = ov;
          bi = ok;
        }
      }
      bk[rj] = bi;
    }

    // gather + straight-through update
#pragma unroll
    for (int rj = 0; rj < 8; ++rj) {
      const int r = wv * 8 + rj;
      const float q = etg[((long)((l << 9) + bk[rj])) * 64 + lane];
      const float res = resL[r][lane];
      const float t = q - res;
      const float qst = res + t;
      dloc = fmaf(t, t, dloc);
      resL[r][lane] = res - qst;
      if (l == 0) buf[(row0 + r) * (long)SB + lane] = qst;
    }
  }

#pragma unroll
  for (int m = 1; m < 64; m <<= 1) dloc += __shfl_xor(dloc, m, 64);
  if (lane == 0) atomicAdd(dsum, dloc);
}

__global__ void finalize_k(const float* __restrict__ dsum, float* __restrict__ out) {
  if (threadIdx.x == 0 && blockIdx.x == 0)
    out[0] = *dsum * (1.0f / (4.0f * 65536.0f * 64.0f));
}

// ---------------- launch ----------------
extern "C" void kernel_launch(void* const* d_in, const int* in_sizes, int n_in, void* d_out,
                              int out_size, void* d_ws, size_t ws_size, hipStream_t stream) {
  (void)in_sizes; (void)n_in; (void)out_size; (void)ws_size;
  const float* x = (const float*)d_in[0];
  const float* enc_w1 = (const float*)d_in[1];
  const float* enc_b1 = (const float*)d_in[2];
  const float* enc_w2 = (const float*)d_in[3];
  const float* enc_b2 = (const float*)d_in[4];
  const float* enc_w3 = (const float*)d_in[5];
  const float* enc_b3 = (const float*)d_in[6];
  const float* enc_res_wa = (const float*)d_in[7];
  const float* enc_res_ba = (const float*)d_in[8];
  const float* enc_res_wb = (const float*)d_in[9];
  const float* enc_res_bb = (const float*)d_in[10];
  const float* q_w = (const float*)d_in[11];
  const float* q_b = (const float*)d_in[12];
  const float* embeds = (const float*)d_in[13];
  const float* dec_w1 = (const float*)d_in[14];
  const float* dec_b1 = (const float*)d_in[15];
  const float* dec_res_wa = (const float*)d_in[16];
  const float* dec_res_ba = (const float*)d_in[17];
  const float* dec_res_wb = (const float*)d_in[18];
  const float* dec_res_bb = (const float*)d_in[19];
  const float* dec_w2 = (const float*)d_in[20];
  const float* dec_b2 = (const float*)d_in[21];
  const float* dec_w3 = (const float*)d_in[22];
  const float* dec_b3 = (const float*)d_in[23];

  float* ws = (float*)d_ws;
  float* buf = ws;                          // [N][256]
  float* W = ws + (long)NROWS * SB;         // weight/codebook region

  float* dout = (float*)d_out;

  prep_k<<<(PREP_N + 255) / 256, 256, 0, stream>>>(enc_w1, enc_w2, enc_w3, q_w, dec_w1, dec_w2,
                                                   dec_w3, enc_res_wa, enc_res_wb, dec_res_wa,
                                                   dec_res_wb, embeds, W);

  const int GB = NROWS / 32;   // 2048 blocks (conv2, vq)
  const int GR = NROWS / 64;   // 1024 blocks (conv6, resblock pairs)

  // encoder
  conv2_k<165, 168, 128, 2, 165, SB, false, true><<<GB, 256, 0, stream>>>(x, W + OFF_WT1, enc_b1, buf);
  conv2_k<128, 128, 256, 4, SB, SB, false, true><<<GB, 256, 0, stream>>>(buf, W + OFF_WT2, enc_b2, buf);
  conv6_k<256, 256, 256, SB, SB, false, false><<<GR, 512, 0, stream>>>(buf, W + OFF_WT3, enc_b3, buf);
  resblock_pair_k<<<GR, 512, 0, stream>>>(buf, W + OFF_WAPE, enc_res_ba, W + OFF_WBTE, enc_res_bb);
  conv2_k<256, 256, 64, 1, SB, SB, true, false><<<GB, 256, 0, stream>>>(buf, W + OFF_WTQ, q_b, buf);

  // residual VQ
  vq_k<<<GB, 256, 0, stream>>>(buf, embeds, W + OFF_EN2, W + OFF_ETG, W + OFF_DSUM);

  // decoder
  conv2_k<64, 64, 256, 4, SB, SB, false, false><<<GB, 256, 0, stream>>>(buf, W + OFF_WTD1, dec_b1, buf);
  resblock_pair_k<<<GR, 512, 0, stream>>>(buf, W + OFF_WAPD, dec_res_ba, W + OFF_WBTD, dec_res_bb);
  conv2_k<256, 256, 128, 2, SB, SB, true, true><<<GB, 256, 0, stream>>>(buf, W + OFF_WTD2, dec_b2, buf);
  conv2_k<128, 128, 165, 4, SB, 165, false, false><<<GB, 256, 0, stream>>>(buf, W + OFF_WTD3, dec_b3, dout);

  finalize_k<<<1, 64, 0, stream>>>(W + OFF_DSUM, dout + (long)NROWS * 165);
}

// Round 12
// 1170.823 us; speedup vs baseline: 1.4162x; 1.0436x over previous
//
#include <hip/hip_runtime.h>

#define NROWS 65536
#define SB 256  // stride of the main ws activation buffer

__device__ __forceinline__ float frelu(float v) { return fmaxf(v, 0.f); }

// ---------------- ws layout (floats, relative to weight region W) ----------------
#define OFF_WT1   0        // [168][128]  enc_w1^T
#define OFF_WT2   21504    // [128][256]  enc_w2^T
#define OFF_WT3   54272    // [256][256]  enc_w3^T
#define OFF_WTQ   119808   // [256][64]   q_w^T
#define OFF_WTD1  136192   // [64][256]   dec_w1^T
#define OFF_WTD2  152576   // [256][128]  dec_w2^T
#define OFF_WTD3  185344   // [128][256]  dec_w3^T (o>=165 zero-padded)
#define OFF_WAPE  218112   // [2][64][32][4] enc_res_wa packed
#define OFF_WBTE  234496   // [2][32][256]   enc_res_wb^T
#define OFF_WAPD  250880   // [2][64][32][4] dec_res_wa packed
#define OFF_WBTD  267264   // [2][32][256]   dec_res_wb^T
#define OFF_ETG   283648   // [4][512][64]  codebook row-major
#define OFF_EN2   414720   // [4][512]      ||e_k||^2
#define OFF_DSUM  416768   // [1]
#define PREP_N    416769

// ---------------- fused prep kernel ----------------
__global__ void prep_k(const float* __restrict__ ew1, const float* __restrict__ ew2,
                       const float* __restrict__ ew3, const float* __restrict__ qw,
                       const float* __restrict__ dw1, const float* __restrict__ dw2,
                       const float* __restrict__ dw3, const float* __restrict__ ewa,
                       const float* __restrict__ ewb, const float* __restrict__ dwa,
                       const float* __restrict__ dwb, const float* __restrict__ embeds,
                       float* __restrict__ W) {
  int idx = blockIdx.x * 256 + threadIdx.x;
  if (idx < 21504) {  // wT1 [168][128] <- ew1 [128][165]
    int k = idx >> 7, o = idx & 127;
    W[OFF_WT1 + idx] = (k < 165) ? ew1[o * 165 + k] : 0.f;
    return;
  }
  idx -= 21504;
  if (idx < 32768) {  // wT2 [128][256]
    int k = idx >> 8, o = idx & 255;
    W[OFF_WT2 + idx] = ew2[o * 128 + k];
    return;
  }
  idx -= 32768;
  if (idx < 65536) {  // wT3 [256][256]
    int k = idx >> 8, o = idx & 255;
    W[OFF_WT3 + idx] = ew3[o * 256 + k];
    return;
  }
  idx -= 65536;
  if (idx < 16384) {  // wTq [256][64]
    int k = idx >> 6, o = idx & 63;
    W[OFF_WTQ + idx] = qw[o * 256 + k];
    return;
  }
  idx -= 16384;
  if (idx < 16384) {  // wTd1 [64][256]
    int k = idx >> 8, o = idx & 255;
    W[OFF_WTD1 + idx] = dw1[o * 64 + k];
    return;
  }
  idx -= 16384;
  if (idx < 32768) {  // wTd2 [256][128]
    int k = idx >> 7, o = idx & 127;
    W[OFF_WTD2 + idx] = dw2[o * 256 + k];
    return;
  }
  idx -= 32768;
  if (idx < 32768) {  // wTd3 [128][256], pad o>=165
    int k = idx >> 8, o = idx & 255;
    W[OFF_WTD3 + idx] = (o < 165) ? dw3[o * 128 + k] : 0.f;
    return;
  }
  idx -= 32768;
  if (idx < 16384) {  // waPe
    int l = idx >> 13, rem = idx & 8191;
    int k4 = rem >> 7, rem2 = rem & 127, o = rem2 >> 2, kk = rem2 & 3;
    W[OFF_WAPE + idx] = ewa[l * 8192 + o * 256 + k4 * 4 + kk];
    return;
  }
  idx -= 16384;
  if (idx < 16384) {  // wbTe
    int l = idx >> 13, rem = idx & 8191;
    int k = rem >> 8, o = rem & 255;
    W[OFF_WBTE + idx] = ewb[l * 8192 + o * 32 + k];
    return;
  }
  idx -= 16384;
  if (idx < 16384) {  // waPd
    int l = idx >> 13, rem = idx & 8191;
    int k4 = rem >> 7, rem2 = rem & 127, o = rem2 >> 2, kk = rem2 & 3;
    W[OFF_WAPD + idx] = dwa[l * 8192 + o * 256 + k4 * 4 + kk];
    return;
  }
  idx -= 16384;
  if (idx < 16384) {  // wbTd
    int l = idx >> 13, rem = idx & 8191;
    int k = rem >> 8, o = rem & 255;
    W[OFF_WBTD + idx] = dwb[l * 8192 + o * 32 + k];
    return;
  }
  idx -= 16384;
  if (idx < 131072) {  // etg[l][k][d]
    int d = idx & 63, k = (idx >> 6) & 511, l = idx >> 15;
    W[OFF_ETG + idx] = embeds[(l * 64 + d) * 512 + k];
    return;
  }
  idx -= 131072;
  if (idx < 2048) {  // en2
    int l = idx >> 9, k = idx & 511;
    float s = 0.f;
    for (int d = 0; d < 64; ++d) {
      float e = embeds[(l * 64 + d) * 512 + k];
      s = fmaf(e, e, s);
    }
    W[OFF_EN2 + idx] = s;
    return;
  }
  idx -= 2048;
  if (idx == 0) W[OFF_DSUM] = 0.f;
}

// ---------------- conv2_k: R6 proven form (LDS x-stage, lane=output) ----------------
template <int CIN, int CINP, int COUT, int CP, int INSTRIDE, int OUTSTRIDE, bool RELU_IN,
          bool RELU_OUT>
__global__ __launch_bounds__(256, 4) void conv2_k(const float* in, const float* __restrict__ wT,
                                                  const float* __restrict__ b, float* out) {
  constexpr int COUTP = 64 * CP;
  constexpr bool GUARD = (COUT != COUTP);
  typedef float vCP __attribute__((ext_vector_type(CP)));
  __shared__ float xs[32][CINP];
  const int tid = threadIdx.x, lane = tid & 63, wv = tid >> 6;
  const long row0 = (long)blockIdx.x * 32;

  for (int i = tid; i < 32 * CINP; i += 256) {
    const int r = i / CINP, c = i % CINP;
    float v = (CIN == CINP || c < CIN) ? in[(row0 + r) * (long)INSTRIDE + c] : 0.f;
    if (RELU_IN) v = frelu(v);
    xs[r][c] = v;
  }
  __syncthreads();

  float acc[8][CP];
#pragma unroll
  for (int i = 0; i < 8; ++i)
#pragma unroll
    for (int j = 0; j < CP; ++j) acc[i][j] = 0.f;

  const float* wbase = wT + lane * CP;
#pragma unroll 4
  for (int k0 = 0; k0 < CINP; k0 += 4) {
    vCP wk[4];
#pragma unroll
    for (int kk = 0; kk < 4; ++kk) wk[kk] = *(const vCP*)(wbase + (k0 + kk) * COUTP);
#pragma unroll
    for (int rj = 0; rj < 8; ++rj) {
      const float4 x = *(const float4*)(&xs[wv * 8 + rj][k0]);
#pragma unroll
      for (int j = 0; j < CP; ++j) {
        acc[rj][j] = fmaf(x.x, wk[0][j], acc[rj][j]);
        acc[rj][j] = fmaf(x.y, wk[1][j], acc[rj][j]);
        acc[rj][j] = fmaf(x.z, wk[2][j], acc[rj][j]);
        acc[rj][j] = fmaf(x.w, wk[3][j], acc[rj][j]);
      }
    }
  }

  float bias[CP];
#pragma unroll
  for (int j = 0; j < CP; ++j) {
    const int o = lane * CP + j;
    bias[j] = (!GUARD || o < COUT) ? b[o] : 0.f;
  }
#pragma unroll
  for (int rj = 0; rj < 8; ++rj) {
    const long rbase = (row0 + wv * 8 + rj) * (long)OUTSTRIDE;
    if constexpr (!GUARD) {
      vCP v;
#pragma unroll
      for (int j = 0; j < CP; ++j) {
        const float t = acc[rj][j] + bias[j];
        v[j] = RELU_OUT ? frelu(t) : t;
      }
      *(vCP*)(out + rbase + lane * CP) = v;
    } else {
#pragma unroll
      for (int j = 0; j < CP; ++j) {
        const int o = lane * CP + j;
        if (o < COUT) {
          const float t = acc[rj][j] + bias[j];
          out[rbase + o] = RELU_OUT ? frelu(t) : t;
        }
      }
    }
  }
}

// ---------------- conv6_k: per-tile TRANSPOSED x (lane = row), scalar weights --------
// (R11 verified on enc3.) 64 rows/block, 512 threads. See R11 notes.
template <int CIN, int COUT, int COUTP, int INSTRIDE, int OUTSTRIDE, bool RELU_IN, bool RELU_OUT>
__global__ __launch_bounds__(512, 2) void conv6_k(const float* __restrict__ in,
                                                  const float* __restrict__ wT,
                                                  const float* __restrict__ b,
                                                  float* __restrict__ out) {
  constexpr int MAXD = (CIN > COUT) ? CIN : COUT;
  __shared__ float lds[MAXD * 65];
  const int tid = threadIdx.x;
  const int lane = tid & 63;
  const int wv = __builtin_amdgcn_readfirstlane(tid >> 6);
  const long row0 = (long)blockIdx.x * 64;

  constexpr int C4 = CIN / 4;
  for (int i = tid; i < 64 * C4; i += 512) {
    const int r = i / C4, c4 = i % C4;
    float4 v = *(const float4*)(in + (row0 + r) * (long)INSTRIDE + c4 * 4);
    if (RELU_IN) {
      v.x = frelu(v.x);
      v.y = frelu(v.y);
      v.z = frelu(v.z);
      v.w = frelu(v.w);
    }
    lds[(c4 * 4 + 0) * 65 + r] = v.x;
    lds[(c4 * 4 + 1) * 65 + r] = v.y;
    lds[(c4 * 4 + 2) * 65 + r] = v.z;
    lds[(c4 * 4 + 3) * 65 + r] = v.w;
  }
  __syncthreads();

  float acc[32];
#pragma unroll
  for (int j = 0; j < 32; ++j) acc[j] = 0.f;

  const float* wrow = wT + wv * 32;
#pragma unroll 2
  for (int k = 0; k < CIN; ++k) {
    const float xv = lds[k * 65 + lane];
    const float* wk = wrow + (long)k * COUTP;
#pragma unroll
    for (int j = 0; j < 32; ++j) acc[j] = fmaf(xv, wk[j], acc[j]);
  }

  const float* bb = b + wv * 32;
#pragma unroll
  for (int j = 0; j < 32; ++j) {
    float t = acc[j] + bb[j];
    acc[j] = RELU_OUT ? frelu(t) : t;
  }

  __syncthreads();
#pragma unroll
  for (int j = 0; j < 32; ++j) lds[(wv * 32 + j) * 65 + lane] = acc[j];
  __syncthreads();

  constexpr int O4 = COUT / 4;
  for (int i = tid; i < 64 * O4; i += 512) {
    const int r = i / O4, c4 = i % O4;
    float4 v;
    v.x = lds[(c4 * 4 + 0) * 65 + r];
    v.y = lds[(c4 * 4 + 1) * 65 + r];
    v.z = lds[(c4 * 4 + 2) * 65 + r];
    v.w = lds[(c4 * 4 + 3) * 65 + r];
    *(float4*)(out + (row0 + r) * (long)OUTSTRIDE + c4 * 4) = v;
  }
}

// ---------------- fused ResBlock PAIR, weights staged in LDS (proven R6) ----------------
__global__ __launch_bounds__(512, 4) void resblock_pair_k(
    float* xbuf, const float* __restrict__ waP, const float* __restrict__ ba,
    const float* __restrict__ wbT, const float* __restrict__ bb) {
  __shared__ float wls[8192];
  __shared__ float ts[64][36];
  const int tid = threadIdx.x, lane = tid & 63, wv = tid >> 6;
  const long row0 = (long)blockIdx.x * 64;
  const int o32 = lane & 31, rh = lane >> 5;

  for (int li = 0; li < 2; ++li) {
    __syncthreads();
    for (int i = tid; i < 8192; i += 512) wls[i] = waP[li * 8192 + i];
    __syncthreads();

    {
      float a0 = 0.f, a1 = 0.f, a2 = 0.f, a3 = 0.f;
      const float* xrow = xbuf + (row0 + wv * 8 + rh * 4) * (long)SB;
#pragma unroll 4
      for (int k0 = 0; k0 < 256; k0 += 4) {
        const float4 wq = *(const float4*)(&wls[k0 * 32 + o32 * 4]);
        const float4 x0 = *(const float4*)(xrow + 0 * SB + k0);
        const float4 x1 = *(const float4*)(xrow + 1 * SB + k0);
        const float4 x2 = *(const float4*)(xrow + 2 * SB + k0);
        const float4 x3 = *(const float4*)(xrow + 3 * SB + k0);
        a0 = fmaf(frelu(x0.x), wq.x, a0);
        a0 = fmaf(frelu(x0.y), wq.y, a0);
        a0 = fmaf(frelu(x0.z), wq.z, a0);
        a0 = fmaf(frelu(x0.w), wq.w, a0);
        a1 = fmaf(frelu(x1.x), wq.x, a1);
        a1 = fmaf(frelu(x1.y), wq.y, a1);
        a1 = fmaf(frelu(x1.z), wq.z, a1);
        a1 = fmaf(frelu(x1.w), wq.w, a1);
        a2 = fmaf(frelu(x2.x), wq.x, a2);
        a2 = fmaf(frelu(x2.y), wq.y, a2);
        a2 = fmaf(frelu(x2.z), wq.z, a2);
        a2 = fmaf(frelu(x2.w), wq.w, a2);
        a3 = fmaf(frelu(x3.x), wq.x, a3);
        a3 = fmaf(frelu(x3.y), wq.y, a3);
        a3 = fmaf(frelu(x3.z), wq.z, a3);
        a3 = fmaf(frelu(x3.w), wq.w, a3);
      }
      const float bal = ba[li * 32 + o32];
      const int rB = wv * 8 + rh * 4;
      ts[rB + 0][o32] = frelu(a0 + bal);
      ts[rB + 1][o32] = frelu(a1 + bal);
      ts[rB + 2][o32] = frelu(a2 + bal);
      ts[rB + 3][o32] = frelu(a3 + bal);
    }

    __syncthreads();
    for (int i = tid; i < 8192; i += 512) wls[i] = wbT[li * 8192 + i];
    __syncthreads();

    float acc2[8][4];
#pragma unroll
    for (int i = 0; i < 8; ++i)
#pragma unroll
      for (int j = 0; j < 4; ++j) acc2[i][j] = 0.f;

#pragma unroll
    for (int k0 = 0; k0 < 32; k0 += 4) {
      const float4 wk0 = *(const float4*)(&wls[(k0 + 0) * 256 + lane * 4]);
      const float4 wk1 = *(const float4*)(&wls[(k0 + 1) * 256 + lane * 4]);
      const float4 wk2 = *(const float4*)(&wls[(k0 + 2) * 256 + lane * 4]);
      const float4 wk3 = *(const float4*)(&wls[(k0 + 3) * 256 + lane * 4]);
#pragma unroll
      for (int rj = 0; rj < 8; ++rj) {
        const float4 t4 = *(const float4*)(&ts[wv * 8 + rj][k0]);
        acc2[rj][0] = fmaf(t4.x, wk0.x, acc2[rj][0]);
        acc2[rj][1] = fmaf(t4.x, wk0.y, acc2[rj][1]);
        acc2[rj][2] = fmaf(t4.x, wk0.z, acc2[rj][2]);
        acc2[rj][3] = fmaf(t4.x, wk0.w, acc2[rj][3]);
        acc2[rj][0] = fmaf(t4.y, wk1.x, acc2[rj][0]);
        acc2[rj][1] = fmaf(t4.y, wk1.y, acc2[rj][1]);
        acc2[rj][2] = fmaf(t4.y, wk1.z, acc2[rj][2]);
        acc2[rj][3] = fmaf(t4.y, wk1.w, acc2[rj][3]);
        acc2[rj][0] = fmaf(t4.z, wk2.x, acc2[rj][0]);
        acc2[rj][1] = fmaf(t4.z, wk2.y, acc2[rj][1]);
        acc2[rj][2] = fmaf(t4.z, wk2.z, acc2[rj][2]);
        acc2[rj][3] = fmaf(t4.z, wk2.w, acc2[rj][3]);
        acc2[rj][0] = fmaf(t4.w, wk3.x, acc2[rj][0]);
        acc2[rj][1] = fmaf(t4.w, wk3.y, acc2[rj][1]);
        acc2[rj][2] = fmaf(t4.w, wk3.z, acc2[rj][2]);
        acc2[rj][3] = fmaf(t4.w, wk3.w, acc2[rj][3]);
      }
    }
    const float4 bbv = *(const float4*)(bb + li * 256 + lane * 4);
#pragma unroll
    for (int rj = 0; rj < 8; ++rj) {
      float* xp = xbuf + (row0 + wv * 8 + rj) * (long)SB + lane * 4;
      const float4 xv = *(const float4*)xp;
      float4 nv;
      nv.x = xv.x + acc2[rj][0] + bbv.x;
      nv.y = xv.y + acc2[rj][1] + bbv.y;
      nv.z = xv.z + acc2[rj][2] + bbv.z;
      nv.w = xv.w + acc2[rj][3] + bbv.w;
      *(float4*)xp = nv;
    }
  }
}

// ---------------- FUSED: q-conv head + residual VQ (exact R6 body) + dec1 tail --------
// Removes 2 dispatches + 3 buf round-trips. Rows strictly per-wave after the
// single staging barrier. q-conv: quant = wTq . relu(h) + qb (fp32, k ascending,
// same order as the standalone conv2 it replaces). VQ body byte-identical to the
// proven R6 kernel (first-min tie-break, etg gather, straight-through). main_q
// kept in LDS (mq) and consumed by dec1: out = wTd1 . mq + d1b (256-wide, no relu).
// In-place on buf: all global reads (stage) precede all global writes (dec1 out).
__global__ __launch_bounds__(256, 3) void vq_fused_k(
    float* buf, const float* __restrict__ wTq, const float* __restrict__ qb,
    const float* __restrict__ embeds, const float* __restrict__ en2,
    const float* __restrict__ etg, float* __restrict__ dsum,
    const float* __restrict__ wTd1, const float* __restrict__ d1b) {
  __shared__ float xs[32][256];   // relu(h), 32 KB
  __shared__ float resL[32][68];  // residual, 8.7 KB
  __shared__ float mq[32][68];    // main_q (level-0 q_st), 8.7 KB
  const int tid = threadIdx.x;
  const int lane = tid & 63;
  const int wv = tid >> 6;
  const long row0 = (long)blockIdx.x * 32;

  // ---- stage relu(h) ----
  for (int i = tid; i < 32 * 256; i += 256) {
    const int r = i >> 8, c = i & 255;
    xs[r][c] = frelu(buf[(row0 + r) * (long)SB + c]);
  }
  __syncthreads();

  // ---- q-conv head: quant[r][lane] = sum_k relu(h)[r][k] * wTq[k][lane] + qb ----
  {
    float qacc[8];
#pragma unroll
    for (int i = 0; i < 8; ++i) qacc[i] = 0.f;
#pragma unroll 2
    for (int k0 = 0; k0 < 256; k0 += 4) {
      const float w0 = wTq[(k0 + 0) * 64 + lane];
      const float w1 = wTq[(k0 + 1) * 64 + lane];
      const float w2 = wTq[(k0 + 2) * 64 + lane];
      const float w3 = wTq[(k0 + 3) * 64 + lane];
#pragma unroll
      for (int rj = 0; rj < 8; ++rj) {
        const float4 x = *(const float4*)(&xs[wv * 8 + rj][k0]);
        qacc[rj] = fmaf(x.x, w0, qacc[rj]);
        qacc[rj] = fmaf(x.y, w1, qacc[rj]);
        qacc[rj] = fmaf(x.z, w2, qacc[rj]);
        qacc[rj] = fmaf(x.w, w3, qacc[rj]);
      }
    }
    const float qbv = qb[lane];
#pragma unroll
    for (int rj = 0; rj < 8; ++rj) resL[wv * 8 + rj][lane] = qacc[rj] + qbv;
  }

  // ---- residual VQ (exact R6 body; l==0 writes mq instead of global) ----
  float dloc = 0.f;

  for (int l = 0; l < 4; ++l) {
    float best[8];
    int bk[8];
#pragma unroll
    for (int i = 0; i < 8; ++i) {
      best[i] = 3.4e38f;
      bk[i] = 0;
    }

    for (int kc = 0; kc < 2; ++kc) {
      float acc[8][4];
#pragma unroll
      for (int i = 0; i < 8; ++i)
#pragma unroll
        for (int j = 0; j < 4; ++j) acc[i][j] = 0.f;

      const float* eb = embeds + ((long)l << 15) + (kc << 8) + lane * 4;
#pragma unroll 2
      for (int dq = 0; dq < 16; ++dq) {
        float4 x4[8];
#pragma unroll
        for (int rj = 0; rj < 8; ++rj) x4[rj] = *(const float4*)(&resL[wv * 8 + rj][dq * 4]);
#pragma unroll
        for (int dd = 0; dd < 4; ++dd) {
          const float4 e4 = *(const float4*)(eb + ((dq * 4 + dd) << 9));
#pragma unroll
          for (int rj = 0; rj < 8; ++rj) {
            const float xv = dd == 0 ? x4[rj].x : dd == 1 ? x4[rj].y : dd == 2 ? x4[rj].z : x4[rj].w;
            acc[rj][0] = fmaf(xv, e4.x, acc[rj][0]);
            acc[rj][1] = fmaf(xv, e4.y, acc[rj][1]);
            acc[rj][2] = fmaf(xv, e4.z, acc[rj][2]);
            acc[rj][3] = fmaf(xv, e4.w, acc[rj][3]);
          }
        }
      }

      const float4 e2 = *(const float4*)(en2 + l * 512 + kc * 256 + lane * 4);
#pragma unroll
      for (int rj = 0; rj < 8; ++rj) {
#pragma unroll
        for (int j = 0; j < 4; ++j) {
          const float ev = j == 0 ? e2.x : j == 1 ? e2.y : j == 2 ? e2.z : e2.w;
          const float s = fmaf(-2.f, acc[rj][j], ev);
          const int k = kc * 256 + lane * 4 + j;
          if (s < best[rj]) {
            best[rj] = s;
            bk[rj] = k;
          }
        }
      }
    }

    // cross-lane first-min argmin
#pragma unroll
    for (int rj = 0; rj < 8; ++rj) {
      float bv = best[rj];
      int bi = bk[rj];
#pragma unroll
      for (int m = 1; m < 64; m <<= 1) {
        const float ov = __shfl_xor(bv, m, 64);
        const int ok = __shfl_xor(bi, m, 64);
        if (ov < bv || (ov == bv && ok < bi)) {
          bv = ov;
          bi = ok;
        }
      }
      bk[rj] = bi;
    }

    // gather + straight-through update
#pragma unroll
    for (int rj = 0; rj < 8; ++rj) {
      const int r = wv * 8 + rj;
      const float q = etg[((long)((l << 9) + bk[rj])) * 64 + lane];
      const float res = resL[r][lane];
      const float t = q - res;
      const float qst = res + t;
      dloc = fmaf(t, t, dloc);
      resL[r][lane] = res - qst;
      if (l == 0) mq[r][lane] = qst;
    }
  }

#pragma unroll
  for (int m = 1; m < 64; m <<= 1) dloc += __shfl_xor(dloc, m, 64);
  if (lane == 0) atomicAdd(dsum, dloc);

  // ---- dec1 tail: buf[r][o] = sum_d mq[r][d] * wTd1[d][o] + d1b[o] (no relu) ----
  {
    float acc1[8][4];
#pragma unroll
    for (int i = 0; i < 8; ++i)
#pragma unroll
      for (int j = 0; j < 4; ++j) acc1[i][j] = 0.f;

    const float* w1base = wTd1 + lane * 4;
#pragma unroll 2
    for (int d = 0; d < 64; d += 2) {
      const float4 wA = *(const float4*)(w1base + (d + 0) * 256);
      const float4 wB = *(const float4*)(w1base + (d + 1) * 256);
#pragma unroll
      for (int rj = 0; rj < 8; ++rj) {
        const int r = wv * 8 + rj;
        const float xA = mq[r][d];
        const float xB = mq[r][d + 1];
        acc1[rj][0] = fmaf(xA, wA.x, acc1[rj][0]);
        acc1[rj][1] = fmaf(xA, wA.y, acc1[rj][1]);
        acc1[rj][2] = fmaf(xA, wA.z, acc1[rj][2]);
        acc1[rj][3] = fmaf(xA, wA.w, acc1[rj][3]);
        acc1[rj][0] = fmaf(xB, wB.x, acc1[rj][0]);
        acc1[rj][1] = fmaf(xB, wB.y, acc1[rj][1]);
        acc1[rj][2] = fmaf(xB, wB.z, acc1[rj][2]);
        acc1[rj][3] = fmaf(xB, wB.w, acc1[rj][3]);
      }
    }
    const float4 bv = *(const float4*)(d1b + lane * 4);
#pragma unroll
    for (int rj = 0; rj < 8; ++rj) {
      float4 v;
      v.x = acc1[rj][0] + bv.x;
      v.y = acc1[rj][1] + bv.y;
      v.z = acc1[rj][2] + bv.z;
      v.w = acc1[rj][3] + bv.w;
      *(float4*)(buf + (row0 + wv * 8 + rj) * (long)SB + lane * 4) = v;
    }
  }
}

// ---------------- FUSED decoder tail: d2 (256->128, relu both) + d3 (128->165) --------
// 32 rows/block, 256 threads. x staged relu'd in LDS; t = relu(w2.x+b2) kept in
// wave-private LDS rows; d3 reads t broadcast and writes the 165-stride output
// with guarded scalar stores. Saves one dispatch + the t round-trip + d3's
// half-used-line buf re-read.
__global__ __launch_bounds__(256, 3) void dec23_k(const float* __restrict__ in,
                                                  const float* __restrict__ wTd2,
                                                  const float* __restrict__ b2,
                                                  const float* __restrict__ wTd3,
                                                  const float* __restrict__ b3,
                                                  float* __restrict__ out) {
  __shared__ float xs[32][256];
  __shared__ float ts[32][132];
  const int tid = threadIdx.x, lane = tid & 63, wv = tid >> 6;
  const long row0 = (long)blockIdx.x * 32;

  for (int i = tid; i < 32 * 256; i += 256) {
    const int r = i >> 8, c = i & 255;
    xs[r][c] = frelu(in[(row0 + r) * (long)SB + c]);
  }
  __syncthreads();

  // phase 1: t[r][o] = relu(sum_k x[r][k] * wTd2[k][o] + b2[o]), o = lane*2..+1
  {
    float a2[8][2];
#pragma unroll
    for (int i = 0; i < 8; ++i) {
      a2[i][0] = 0.f;
      a2[i][1] = 0.f;
    }
    const float* w2base = wTd2 + lane * 2;
#pragma unroll 2
    for (int k0 = 0; k0 < 256; k0 += 4) {
      const float2 w0 = *(const float2*)(w2base + (k0 + 0) * 128);
      const float2 w1 = *(const float2*)(w2base + (k0 + 1) * 128);
      const float2 w2v = *(const float2*)(w2base + (k0 + 2) * 128);
      const float2 w3 = *(const float2*)(w2base + (k0 + 3) * 128);
#pragma unroll
      for (int rj = 0; rj < 8; ++rj) {
        const float4 x = *(const float4*)(&xs[wv * 8 + rj][k0]);
        a2[rj][0] = fmaf(x.x, w0.x, a2[rj][0]);
        a2[rj][1] = fmaf(x.x, w0.y, a2[rj][1]);
        a2[rj][0] = fmaf(x.y, w1.x, a2[rj][0]);
        a2[rj][1] = fmaf(x.y, w1.y, a2[rj][1]);
        a2[rj][0] = fmaf(x.z, w2v.x, a2[rj][0]);
        a2[rj][1] = fmaf(x.z, w2v.y, a2[rj][1]);
        a2[rj][0] = fmaf(x.w, w3.x, a2[rj][0]);
        a2[rj][1] = fmaf(x.w, w3.y, a2[rj][1]);
      }
    }
    const float b20 = b2[lane * 2 + 0];
    const float b21 = b2[lane * 2 + 1];
#pragma unroll
    for (int rj = 0; rj < 8; ++rj) {
      const int r = wv * 8 + rj;
      ts[r][lane * 2 + 0] = frelu(a2[rj][0] + b20);
      ts[r][lane * 2 + 1] = frelu(a2[rj][1] + b21);
    }
  }
  // ts rows are wave-private: no barrier needed

  // phase 2: out[r][o] = sum_k t[r][k] * wTd3[k][o] + b3[o], o = lane*4..+3 (<165)
  {
    float a3[8][4];
#pragma unroll
    for (int i = 0; i < 8; ++i)
#pragma unroll
      for (int j = 0; j < 4; ++j) a3[i][j] = 0.f;

    const float* w3base = wTd3 + lane * 4;
#pragma unroll 2
    for (int k0 = 0; k0 < 128; k0 += 4) {
      const float4 wk0 = *(const float4*)(w3base + (k0 + 0) * 256);
      const float4 wk1 = *(const float4*)(w3base + (k0 + 1) * 256);
      const float4 wk2 = *(const float4*)(w3base + (k0 + 2) * 256);
      const float4 wk3 = *(const float4*)(w3base + (k0 + 3) * 256);
#pragma unroll
      for (int rj = 0; rj < 8; ++rj) {
        const float4 t4 = *(const float4*)(&ts[wv * 8 + rj][k0]);
        a3[rj][0] = fmaf(t4.x, wk0.x, a3[rj][0]);
        a3[rj][1] = fmaf(t4.x, wk0.y, a3[rj][1]);
        a3[rj][2] = fmaf(t4.x, wk0.z, a3[rj][2]);
        a3[rj][3] = fmaf(t4.x, wk0.w, a3[rj][3]);
        a3[rj][0] = fmaf(t4.y, wk1.x, a3[rj][0]);
        a3[rj][1] = fmaf(t4.y, wk1.y, a3[rj][1]);
        a3[rj][2] = fmaf(t4.y, wk1.z, a3[rj][2]);
        a3[rj][3] = fmaf(t4.y, wk1.w, a3[rj][3]);
        a3[rj][0] = fmaf(t4.z, wk2.x, a3[rj][0]);
        a3[rj][1] = fmaf(t4.z, wk2.y, a3[rj][1]);
        a3[rj][2] = fmaf(t4.z, wk2.z, a3[rj][2]);
        a3[rj][3] = fmaf(t4.z, wk2.w, a3[rj][3]);
        a3[rj][0] = fmaf(t4.w, wk3.x, a3[rj][0]);
        a3[rj][1] = fmaf(t4.w, wk3.y, a3[rj][1]);
        a3[rj][2] = fmaf(t4.w, wk3.z, a3[rj][2]);
        a3[rj][3] = fmaf(t4.w, wk3.w, a3[rj][3]);
      }
    }
    float bias[4];
#pragma unroll
    for (int j = 0; j < 4; ++j) {
      const int o = lane * 4 + j;
      bias[j] = (o < 165) ? b3[o] : 0.f;
    }
#pragma unroll
    for (int rj = 0; rj < 8; ++rj) {
      const long rbase = (row0 + wv * 8 + rj) * 165L;
#pragma unroll
      for (int j = 0; j < 4; ++j) {
        const int o = lane * 4 + j;
        if (o < 165) out[rbase + o] = a3[rj][j] + bias[j];
      }
    }
  }
}

__global__ void finalize_k(const float* __restrict__ dsum, float* __restrict__ out) {
  if (threadIdx.x == 0 && blockIdx.x == 0)
    out[0] = *dsum * (1.0f / (4.0f * 65536.0f * 64.0f));
}

// ---------------- launch ----------------
extern "C" void kernel_launch(void* const* d_in, const int* in_sizes, int n_in, void* d_out,
                              int out_size, void* d_ws, size_t ws_size, hipStream_t stream) {
  (void)in_sizes; (void)n_in; (void)out_size; (void)ws_size;
  const float* x = (const float*)d_in[0];
  const float* enc_w1 = (const float*)d_in[1];
  const float* enc_b1 = (const float*)d_in[2];
  const float* enc_w2 = (const float*)d_in[3];
  const float* enc_b2 = (const float*)d_in[4];
  const float* enc_w3 = (const float*)d_in[5];
  const float* enc_b3 = (const float*)d_in[6];
  const float* enc_res_wa = (const float*)d_in[7];
  const float* enc_res_ba = (const float*)d_in[8];
  const float* enc_res_wb = (const float*)d_in[9];
  const float* enc_res_bb = (const float*)d_in[10];
  const float* q_w = (const float*)d_in[11];
  const float* q_b = (const float*)d_in[12];
  const float* embeds = (const float*)d_in[13];
  const float* dec_w1 = (const float*)d_in[14];
  const float* dec_b1 = (const float*)d_in[15];
  const float* dec_res_wa = (const float*)d_in[16];
  const float* dec_res_ba = (const float*)d_in[17];
  const float* dec_res_wb = (const float*)d_in[18];
  const float* dec_res_bb = (const float*)d_in[19];
  const float* dec_w2 = (const float*)d_in[20];
  const float* dec_b2 = (const float*)d_in[21];
  const float* dec_w3 = (const float*)d_in[22];
  const float* dec_b3 = (const float*)d_in[23];

  float* ws = (float*)d_ws;
  float* buf = ws;                          // [N][256]
  float* W = ws + (long)NROWS * SB;         // weight/codebook region

  float* dout = (float*)d_out;

  prep_k<<<(PREP_N + 255) / 256, 256, 0, stream>>>(enc_w1, enc_w2, enc_w3, q_w, dec_w1, dec_w2,
                                                   dec_w3, enc_res_wa, enc_res_wb, dec_res_wa,
                                                   dec_res_wb, embeds, W);

  const int GB = NROWS / 32;   // 2048 blocks (conv2, vq_fused, dec23)
  const int GR = NROWS / 64;   // 1024 blocks (conv6, resblock pairs)

  // encoder
  conv2_k<165, 168, 128, 2, 165, SB, false, true><<<GB, 256, 0, stream>>>(x, W + OFF_WT1, enc_b1, buf);
  conv6_k<128, 256, 256, SB, SB, false, true><<<GR, 512, 0, stream>>>(buf, W + OFF_WT2, enc_b2, buf);
  conv6_k<256, 256, 256, SB, SB, false, false><<<GR, 512, 0, stream>>>(buf, W + OFF_WT3, enc_b3, buf);
  resblock_pair_k<<<GR, 512, 0, stream>>>(buf, W + OFF_WAPE, enc_res_ba, W + OFF_WBTE, enc_res_bb);

  // q-conv + residual VQ + dec1 (fused)
  vq_fused_k<<<GB, 256, 0, stream>>>(buf, W + OFF_WTQ, q_b, embeds, W + OFF_EN2, W + OFF_ETG,
                                     W + OFF_DSUM, W + OFF_WTD1, dec_b1);

  // decoder
  resblock_pair_k<<<GR, 512, 0, stream>>>(buf, W + OFF_WAPD, dec_res_ba, W + OFF_WBTD, dec_res_bb);
  dec23_k<<<GB, 256, 0, stream>>>(buf, W + OFF_WTD2, dec_b2, W + OFF_WTD3, dec_b3, dout);

  finalize_k<<<1, 64, 0, stream>>>(W + OFF_DSUM, dout + (long)NROWS * 165);
}

// Round 13
// 1160.345 us; speedup vs baseline: 1.4290x; 1.0090x over previous
//
#include <hip/hip_runtime.h>

#define NROWS 65536
#define SB 256  // stride of the main ws activation buffer

__device__ __forceinline__ float frelu(float v) { return fmaxf(v, 0.f); }

// ---------------- ws layout (floats, relative to weight region W) ----------------
#define OFF_WT1   0        // [168][128]  enc_w1^T
#define OFF_WT2   21504    // [128][256]  enc_w2^T
#define OFF_WT3   54272    // [256][256]  enc_w3^T
#define OFF_WTQ   119808   // [256][64]   q_w^T
#define OFF_WTD1  136192   // [64][256]   dec_w1^T
#define OFF_WTD2  152576   // [256][128]  dec_w2^T
#define OFF_WTD3  185344   // [128][256]  dec_w3^T (o>=165 zero-padded)
#define OFF_WAPE  218112   // [2][64][32][4] enc_res_wa packed
#define OFF_WBTE  234496   // [2][32][256]   enc_res_wb^T
#define OFF_WAPD  250880   // [2][64][32][4] dec_res_wa packed
#define OFF_WBTD  267264   // [2][32][256]   dec_res_wb^T
#define OFF_ETG   283648   // [4][512][64]  codebook row-major
#define OFF_EN2   414720   // [4][512]      ||e_k||^2
#define OFF_DSUM  416768   // [1]
#define PREP_N    416769

// ---------------- fused prep kernel ----------------
__global__ void prep_k(const float* __restrict__ ew1, const float* __restrict__ ew2,
                       const float* __restrict__ ew3, const float* __restrict__ qw,
                       const float* __restrict__ dw1, const float* __restrict__ dw2,
                       const float* __restrict__ dw3, const float* __restrict__ ewa,
                       const float* __restrict__ ewb, const float* __restrict__ dwa,
                       const float* __restrict__ dwb, const float* __restrict__ embeds,
                       float* __restrict__ W) {
  int idx = blockIdx.x * 256 + threadIdx.x;
  if (idx < 21504) {  // wT1 [168][128] <- ew1 [128][165]
    int k = idx >> 7, o = idx & 127;
    W[OFF_WT1 + idx] = (k < 165) ? ew1[o * 165 + k] : 0.f;
    return;
  }
  idx -= 21504;
  if (idx < 32768) {  // wT2 [128][256]
    int k = idx >> 8, o = idx & 255;
    W[OFF_WT2 + idx] = ew2[o * 128 + k];
    return;
  }
  idx -= 32768;
  if (idx < 65536) {  // wT3 [256][256]
    int k = idx >> 8, o = idx & 255;
    W[OFF_WT3 + idx] = ew3[o * 256 + k];
    return;
  }
  idx -= 65536;
  if (idx < 16384) {  // wTq [256][64]
    int k = idx >> 6, o = idx & 63;
    W[OFF_WTQ + idx] = qw[o * 256 + k];
    return;
  }
  idx -= 16384;
  if (idx < 16384) {  // wTd1 [64][256]
    int k = idx >> 8, o = idx & 255;
    W[OFF_WTD1 + idx] = dw1[o * 64 + k];
    return;
  }
  idx -= 16384;
  if (idx < 32768) {  // wTd2 [256][128]
    int k = idx >> 7, o = idx & 127;
    W[OFF_WTD2 + idx] = dw2[o * 256 + k];
    return;
  }
  idx -= 32768;
  if (idx < 32768) {  // wTd3 [128][256], pad o>=165
    int k = idx >> 8, o = idx & 255;
    W[OFF_WTD3 + idx] = (o < 165) ? dw3[o * 128 + k] : 0.f;
    return;
  }
  idx -= 32768;
  if (idx < 16384) {  // waPe
    int l = idx >> 13, rem = idx & 8191;
    int k4 = rem >> 7, rem2 = rem & 127, o = rem2 >> 2, kk = rem2 & 3;
    W[OFF_WAPE + idx] = ewa[l * 8192 + o * 256 + k4 * 4 + kk];
    return;
  }
  idx -= 16384;
  if (idx < 16384) {  // wbTe
    int l = idx >> 13, rem = idx & 8191;
    int k = rem >> 8, o = rem & 255;
    W[OFF_WBTE + idx] = ewb[l * 8192 + o * 32 + k];
    return;
  }
  idx -= 16384;
  if (idx < 16384) {  // waPd
    int l = idx >> 13, rem = idx & 8191;
    int k4 = rem >> 7, rem2 = rem & 127, o = rem2 >> 2, kk = rem2 & 3;
    W[OFF_WAPD + idx] = dwa[l * 8192 + o * 256 + k4 * 4 + kk];
    return;
  }
  idx -= 16384;
  if (idx < 16384) {  // wbTd
    int l = idx >> 13, rem = idx & 8191;
    int k = rem >> 8, o = rem & 255;
    W[OFF_WBTD + idx] = dwb[l * 8192 + o * 32 + k];
    return;
  }
  idx -= 16384;
  if (idx < 131072) {  // etg[l][k][d]
    int d = idx & 63, k = (idx >> 6) & 511, l = idx >> 15;
    W[OFF_ETG + idx] = embeds[(l * 64 + d) * 512 + k];
    return;
  }
  idx -= 131072;
  if (idx < 2048) {  // en2
    int l = idx >> 9, k = idx & 511;
    float s = 0.f;
    for (int d = 0; d < 64; ++d) {
      float e = embeds[(l * 64 + d) * 512 + k];
      s = fmaf(e, e, s);
    }
    W[OFF_EN2 + idx] = s;
    return;
  }
  idx -= 2048;
  if (idx == 0) W[OFF_DSUM] = 0.f;
}

// ---------------- conv2_k: R6 proven form (LDS x-stage, lane=output) ----------------
template <int CIN, int CINP, int COUT, int CP, int INSTRIDE, int OUTSTRIDE, bool RELU_IN,
          bool RELU_OUT>
__global__ __launch_bounds__(256, 4) void conv2_k(const float* in, const float* __restrict__ wT,
                                                  const float* __restrict__ b, float* out) {
  constexpr int COUTP = 64 * CP;
  constexpr bool GUARD = (COUT != COUTP);
  typedef float vCP __attribute__((ext_vector_type(CP)));
  __shared__ float xs[32][CINP];
  const int tid = threadIdx.x, lane = tid & 63, wv = tid >> 6;
  const long row0 = (long)blockIdx.x * 32;

  for (int i = tid; i < 32 * CINP; i += 256) {
    const int r = i / CINP, c = i % CINP;
    float v = (CIN == CINP || c < CIN) ? in[(row0 + r) * (long)INSTRIDE + c] : 0.f;
    if (RELU_IN) v = frelu(v);
    xs[r][c] = v;
  }
  __syncthreads();

  float acc[8][CP];
#pragma unroll
  for (int i = 0; i < 8; ++i)
#pragma unroll
    for (int j = 0; j < CP; ++j) acc[i][j] = 0.f;

  const float* wbase = wT + lane * CP;
#pragma unroll 4
  for (int k0 = 0; k0 < CINP; k0 += 4) {
    vCP wk[4];
#pragma unroll
    for (int kk = 0; kk < 4; ++kk) wk[kk] = *(const vCP*)(wbase + (k0 + kk) * COUTP);
#pragma unroll
    for (int rj = 0; rj < 8; ++rj) {
      const float4 x = *(const float4*)(&xs[wv * 8 + rj][k0]);
#pragma unroll
      for (int j = 0; j < CP; ++j) {
        acc[rj][j] = fmaf(x.x, wk[0][j], acc[rj][j]);
        acc[rj][j] = fmaf(x.y, wk[1][j], acc[rj][j]);
        acc[rj][j] = fmaf(x.z, wk[2][j], acc[rj][j]);
        acc[rj][j] = fmaf(x.w, wk[3][j], acc[rj][j]);
      }
    }
  }

  float bias[CP];
#pragma unroll
  for (int j = 0; j < CP; ++j) {
    const int o = lane * CP + j;
    bias[j] = (!GUARD || o < COUT) ? b[o] : 0.f;
  }
#pragma unroll
  for (int rj = 0; rj < 8; ++rj) {
    const long rbase = (row0 + wv * 8 + rj) * (long)OUTSTRIDE;
    if constexpr (!GUARD) {
      vCP v;
#pragma unroll
      for (int j = 0; j < CP; ++j) {
        const float t = acc[rj][j] + bias[j];
        v[j] = RELU_OUT ? frelu(t) : t;
      }
      *(vCP*)(out + rbase + lane * CP) = v;
    } else {
#pragma unroll
      for (int j = 0; j < CP; ++j) {
        const int o = lane * CP + j;
        if (o < COUT) {
          const float t = acc[rj][j] + bias[j];
          out[rbase + o] = RELU_OUT ? frelu(t) : t;
        }
      }
    }
  }
}

// ---------------- conv6_k: per-tile TRANSPOSED x (lane = row), scalar weights --------
template <int CIN, int COUT, int COUTP, int INSTRIDE, int OUTSTRIDE, bool RELU_IN, bool RELU_OUT>
__global__ __launch_bounds__(512, 2) void conv6_k(const float* __restrict__ in,
                                                  const float* __restrict__ wT,
                                                  const float* __restrict__ b,
                                                  float* __restrict__ out) {
  constexpr int MAXD = (CIN > COUT) ? CIN : COUT;
  __shared__ float lds[MAXD * 65];
  const int tid = threadIdx.x;
  const int lane = tid & 63;
  const int wv = __builtin_amdgcn_readfirstlane(tid >> 6);
  const long row0 = (long)blockIdx.x * 64;

  constexpr int C4 = CIN / 4;
  for (int i = tid; i < 64 * C4; i += 512) {
    const int r = i / C4, c4 = i % C4;
    float4 v = *(const float4*)(in + (row0 + r) * (long)INSTRIDE + c4 * 4);
    if (RELU_IN) {
      v.x = frelu(v.x);
      v.y = frelu(v.y);
      v.z = frelu(v.z);
      v.w = frelu(v.w);
    }
    lds[(c4 * 4 + 0) * 65 + r] = v.x;
    lds[(c4 * 4 + 1) * 65 + r] = v.y;
    lds[(c4 * 4 + 2) * 65 + r] = v.z;
    lds[(c4 * 4 + 3) * 65 + r] = v.w;
  }
  __syncthreads();

  float acc[32];
#pragma unroll
  for (int j = 0; j < 32; ++j) acc[j] = 0.f;

  const float* wrow = wT + wv * 32;
#pragma unroll 2
  for (int k = 0; k < CIN; ++k) {
    const float xv = lds[k * 65 + lane];
    const float* wk = wrow + (long)k * COUTP;
#pragma unroll
    for (int j = 0; j < 32; ++j) acc[j] = fmaf(xv, wk[j], acc[j]);
  }

  const float* bb = b + wv * 32;
#pragma unroll
  for (int j = 0; j < 32; ++j) {
    float t = acc[j] + bb[j];
    acc[j] = RELU_OUT ? frelu(t) : t;
  }

  __syncthreads();
#pragma unroll
  for (int j = 0; j < 32; ++j) lds[(wv * 32 + j) * 65 + lane] = acc[j];
  __syncthreads();

  constexpr int O4 = COUT / 4;
  for (int i = tid; i < 64 * O4; i += 512) {
    const int r = i / O4, c4 = i % O4;
    float4 v;
    v.x = lds[(c4 * 4 + 0) * 65 + r];
    v.y = lds[(c4 * 4 + 1) * 65 + r];
    v.z = lds[(c4 * 4 + 2) * 65 + r];
    v.w = lds[(c4 * 4 + 3) * 65 + r];
    *(float4*)(out + (row0 + r) * (long)OUTSTRIDE + c4 * 4) = v;
  }
}

// ---------------- fused ResBlock PAIR, weights staged in LDS (proven R6) ----------------
__global__ __launch_bounds__(512, 4) void resblock_pair_k(
    float* xbuf, const float* __restrict__ waP, const float* __restrict__ ba,
    const float* __restrict__ wbT, const float* __restrict__ bb) {
  __shared__ float wls[8192];
  __shared__ float ts[64][36];
  const int tid = threadIdx.x, lane = tid & 63, wv = tid >> 6;
  const long row0 = (long)blockIdx.x * 64;
  const int o32 = lane & 31, rh = lane >> 5;

  for (int li = 0; li < 2; ++li) {
    __syncthreads();
    for (int i = tid; i < 8192; i += 512) wls[i] = waP[li * 8192 + i];
    __syncthreads();

    {
      float a0 = 0.f, a1 = 0.f, a2 = 0.f, a3 = 0.f;
      const float* xrow = xbuf + (row0 + wv * 8 + rh * 4) * (long)SB;
#pragma unroll 4
      for (int k0 = 0; k0 < 256; k0 += 4) {
        const float4 wq = *(const float4*)(&wls[k0 * 32 + o32 * 4]);
        const float4 x0 = *(const float4*)(xrow + 0 * SB + k0);
        const float4 x1 = *(const float4*)(xrow + 1 * SB + k0);
        const float4 x2 = *(const float4*)(xrow + 2 * SB + k0);
        const float4 x3 = *(const float4*)(xrow + 3 * SB + k0);
        a0 = fmaf(frelu(x0.x), wq.x, a0);
        a0 = fmaf(frelu(x0.y), wq.y, a0);
        a0 = fmaf(frelu(x0.z), wq.z, a0);
        a0 = fmaf(frelu(x0.w), wq.w, a0);
        a1 = fmaf(frelu(x1.x), wq.x, a1);
        a1 = fmaf(frelu(x1.y), wq.y, a1);
        a1 = fmaf(frelu(x1.z), wq.z, a1);
        a1 = fmaf(frelu(x1.w), wq.w, a1);
        a2 = fmaf(frelu(x2.x), wq.x, a2);
        a2 = fmaf(frelu(x2.y), wq.y, a2);
        a2 = fmaf(frelu(x2.z), wq.z, a2);
        a2 = fmaf(frelu(x2.w), wq.w, a2);
        a3 = fmaf(frelu(x3.x), wq.x, a3);
        a3 = fmaf(frelu(x3.y), wq.y, a3);
        a3 = fmaf(frelu(x3.z), wq.z, a3);
        a3 = fmaf(frelu(x3.w), wq.w, a3);
      }
      const float bal = ba[li * 32 + o32];
      const int rB = wv * 8 + rh * 4;
      ts[rB + 0][o32] = frelu(a0 + bal);
      ts[rB + 1][o32] = frelu(a1 + bal);
      ts[rB + 2][o32] = frelu(a2 + bal);
      ts[rB + 3][o32] = frelu(a3 + bal);
    }

    __syncthreads();
    for (int i = tid; i < 8192; i += 512) wls[i] = wbT[li * 8192 + i];
    __syncthreads();

    float acc2[8][4];
#pragma unroll
    for (int i = 0; i < 8; ++i)
#pragma unroll
      for (int j = 0; j < 4; ++j) acc2[i][j] = 0.f;

#pragma unroll
    for (int k0 = 0; k0 < 32; k0 += 4) {
      const float4 wk0 = *(const float4*)(&wls[(k0 + 0) * 256 + lane * 4]);
      const float4 wk1 = *(const float4*)(&wls[(k0 + 1) * 256 + lane * 4]);
      const float4 wk2 = *(const float4*)(&wls[(k0 + 2) * 256 + lane * 4]);
      const float4 wk3 = *(const float4*)(&wls[(k0 + 3) * 256 + lane * 4]);
#pragma unroll
      for (int rj = 0; rj < 8; ++rj) {
        const float4 t4 = *(const float4*)(&ts[wv * 8 + rj][k0]);
        acc2[rj][0] = fmaf(t4.x, wk0.x, acc2[rj][0]);
        acc2[rj][1] = fmaf(t4.x, wk0.y, acc2[rj][1]);
        acc2[rj][2] = fmaf(t4.x, wk0.z, acc2[rj][2]);
        acc2[rj][3] = fmaf(t4.x, wk0.w, acc2[rj][3]);
        acc2[rj][0] = fmaf(t4.y, wk1.x, acc2[rj][0]);
        acc2[rj][1] = fmaf(t4.y, wk1.y, acc2[rj][1]);
        acc2[rj][2] = fmaf(t4.y, wk1.z, acc2[rj][2]);
        acc2[rj][3] = fmaf(t4.y, wk1.w, acc2[rj][3]);
        acc2[rj][0] = fmaf(t4.z, wk2.x, acc2[rj][0]);
        acc2[rj][1] = fmaf(t4.z, wk2.y, acc2[rj][1]);
        acc2[rj][2] = fmaf(t4.z, wk2.z, acc2[rj][2]);
        acc2[rj][3] = fmaf(t4.z, wk2.w, acc2[rj][3]);
        acc2[rj][0] = fmaf(t4.w, wk3.x, acc2[rj][0]);
        acc2[rj][1] = fmaf(t4.w, wk3.y, acc2[rj][1]);
        acc2[rj][2] = fmaf(t4.w, wk3.z, acc2[rj][2]);
        acc2[rj][3] = fmaf(t4.w, wk3.w, acc2[rj][3]);
      }
    }
    const float4 bbv = *(const float4*)(bb + li * 256 + lane * 4);
#pragma unroll
    for (int rj = 0; rj < 8; ++rj) {
      float* xp = xbuf + (row0 + wv * 8 + rj) * (long)SB + lane * 4;
      const float4 xv = *(const float4*)xp;
      float4 nv;
      nv.x = xv.x + acc2[rj][0] + bbv.x;
      nv.y = xv.y + acc2[rj][1] + bbv.y;
      nv.z = xv.z + acc2[rj][2] + bbv.z;
      nv.w = xv.w + acc2[rj][3] + bbv.w;
      *(float4*)xp = nv;
    }
  }
}

// ---------------- FUSED: q-conv + residual VQ (kc-fused 8 codes) + dec1 --------------
// R12 @ 409us, VALU 62%, Occ 30.6% (3 blk/CU, LDS 50KB). Two fixes:
// (1) resL/mq ALIAS INTO xs: after q-conv consumes a row, xs[r][128..255] is dead.
//     resL := xs[r][128+d], mq := xs[r][192+d]. Per-wave sequencing makes this safe
//     (the resL write value data-depends on all xs reads; DS ops in-order per wave;
//     rows are wave-private after the one staging barrier). LDS 50176 -> 32768
//     => 4 blocks/CU (16 waves, VGPR-capped).
// (2) kc-FUSED VQ body {8 rows, 8 codes/lane}: one resL float4 read feeds 32 FMA
//     (was 16) -> LDS pipe ratio 1.5x -> 0.75x. Live regs ~110 (best/bk init moved
//     after the dot loop) under the minw=2 cap of 128. Scoring processes k ascending
//     (kc0 j0..3 then kc1 j0..3) -> identical first-min tie-break (R9-proven).
__global__ __launch_bounds__(256, 2) void vq_fused_k(
    float* buf, const float* __restrict__ wTq, const float* __restrict__ qb,
    const float* __restrict__ embeds, const float* __restrict__ en2,
    const float* __restrict__ etg, float* __restrict__ dsum,
    const float* __restrict__ wTd1, const float* __restrict__ d1b) {
  __shared__ float xs[32][256];  // [0..255]=relu(h); later [128..191]=resL, [192..255]=mq
  const int tid = threadIdx.x;
  const int lane = tid & 63;
  const int wv = tid >> 6;
  const long row0 = (long)blockIdx.x * 32;

  // ---- stage relu(h) ----
  for (int i = tid; i < 32 * 256; i += 256) {
    const int r = i >> 8, c = i & 255;
    xs[r][c] = frelu(buf[(row0 + r) * (long)SB + c]);
  }
  __syncthreads();

  // ---- q-conv head: resL[r][lane] = sum_k relu(h)[r][k] * wTq[k][lane] + qb ----
  {
    float qacc[8];
#pragma unroll
    for (int i = 0; i < 8; ++i) qacc[i] = 0.f;
#pragma unroll 2
    for (int k0 = 0; k0 < 256; k0 += 4) {
      const float w0 = wTq[(k0 + 0) * 64 + lane];
      const float w1 = wTq[(k0 + 1) * 64 + lane];
      const float w2 = wTq[(k0 + 2) * 64 + lane];
      const float w3 = wTq[(k0 + 3) * 64 + lane];
#pragma unroll
      for (int rj = 0; rj < 8; ++rj) {
        const float4 x = *(const float4*)(&xs[wv * 8 + rj][k0]);
        qacc[rj] = fmaf(x.x, w0, qacc[rj]);
        qacc[rj] = fmaf(x.y, w1, qacc[rj]);
        qacc[rj] = fmaf(x.z, w2, qacc[rj]);
        qacc[rj] = fmaf(x.w, w3, qacc[rj]);
      }
    }
    const float qbv = qb[lane];
    // write resL into the now-dead xs[r][128..191] (value depends on all reads above)
#pragma unroll
    for (int rj = 0; rj < 8; ++rj) xs[wv * 8 + rj][128 + lane] = qacc[rj] + qbv;
  }

  // ---- residual VQ: kc-fused, 8 codes/lane ----
  float dloc = 0.f;

  for (int l = 0; l < 4; ++l) {
    float acc[8][8];
#pragma unroll
    for (int i = 0; i < 8; ++i)
#pragma unroll
      for (int j = 0; j < 8; ++j) acc[i][j] = 0.f;

    const float* eb0 = embeds + ((long)l << 15) + lane * 4;  // kc=0 chunk
    const float* eb1 = eb0 + 256;                            // kc=1 chunk

#pragma unroll 2
    for (int dq = 0; dq < 16; ++dq) {
      const float4 ea0 = *(const float4*)(eb0 + ((dq * 4 + 0) << 9));
      const float4 ea1 = *(const float4*)(eb0 + ((dq * 4 + 1) << 9));
      const float4 ea2 = *(const float4*)(eb0 + ((dq * 4 + 2) << 9));
      const float4 ea3 = *(const float4*)(eb0 + ((dq * 4 + 3) << 9));
      const float4 fb0 = *(const float4*)(eb1 + ((dq * 4 + 0) << 9));
      const float4 fb1 = *(const float4*)(eb1 + ((dq * 4 + 1) << 9));
      const float4 fb2 = *(const float4*)(eb1 + ((dq * 4 + 2) << 9));
      const float4 fb3 = *(const float4*)(eb1 + ((dq * 4 + 3) << 9));
#pragma unroll
      for (int rj = 0; rj < 8; ++rj) {
        const float4 x = *(const float4*)(&xs[wv * 8 + rj][128 + dq * 4]);
        acc[rj][0] = fmaf(x.x, ea0.x, acc[rj][0]);
        acc[rj][1] = fmaf(x.x, ea0.y, acc[rj][1]);
        acc[rj][2] = fmaf(x.x, ea0.z, acc[rj][2]);
        acc[rj][3] = fmaf(x.x, ea0.w, acc[rj][3]);
        acc[rj][4] = fmaf(x.x, fb0.x, acc[rj][4]);
        acc[rj][5] = fmaf(x.x, fb0.y, acc[rj][5]);
        acc[rj][6] = fmaf(x.x, fb0.z, acc[rj][6]);
        acc[rj][7] = fmaf(x.x, fb0.w, acc[rj][7]);
        acc[rj][0] = fmaf(x.y, ea1.x, acc[rj][0]);
        acc[rj][1] = fmaf(x.y, ea1.y, acc[rj][1]);
        acc[rj][2] = fmaf(x.y, ea1.z, acc[rj][2]);
        acc[rj][3] = fmaf(x.y, ea1.w, acc[rj][3]);
        acc[rj][4] = fmaf(x.y, fb1.x, acc[rj][4]);
        acc[rj][5] = fmaf(x.y, fb1.y, acc[rj][5]);
        acc[rj][6] = fmaf(x.y, fb1.z, acc[rj][6]);
        acc[rj][7] = fmaf(x.y, fb1.w, acc[rj][7]);
        acc[rj][0] = fmaf(x.z, ea2.x, acc[rj][0]);
        acc[rj][1] = fmaf(x.z, ea2.y, acc[rj][1]);
        acc[rj][2] = fmaf(x.z, ea2.z, acc[rj][2]);
        acc[rj][3] = fmaf(x.z, ea2.w, acc[rj][3]);
        acc[rj][4] = fmaf(x.z, fb2.x, acc[rj][4]);
        acc[rj][5] = fmaf(x.z, fb2.y, acc[rj][5]);
        acc[rj][6] = fmaf(x.z, fb2.z, acc[rj][6]);
        acc[rj][7] = fmaf(x.z, fb2.w, acc[rj][7]);
        acc[rj][0] = fmaf(x.w, ea3.x, acc[rj][0]);
        acc[rj][1] = fmaf(x.w, ea3.y, acc[rj][1]);
        acc[rj][2] = fmaf(x.w, ea3.z, acc[rj][2]);
        acc[rj][3] = fmaf(x.w, ea3.w, acc[rj][3]);
        acc[rj][4] = fmaf(x.w, fb3.x, acc[rj][4]);
        acc[rj][5] = fmaf(x.w, fb3.y, acc[rj][5]);
        acc[rj][6] = fmaf(x.w, fb3.z, acc[rj][6]);
        acc[rj][7] = fmaf(x.w, fb3.w, acc[rj][7]);
      }
    }

    // scores, k ascending (kc0 j0..3, then kc1 j0..3) — first-min tie-break preserved
    float best[8];
    int bk[8];
#pragma unroll
    for (int i = 0; i < 8; ++i) {
      best[i] = 3.4e38f;
      bk[i] = 0;
    }
    const float4 e2a = *(const float4*)(en2 + l * 512 + lane * 4);
    const float4 e2b = *(const float4*)(en2 + l * 512 + 256 + lane * 4);
#pragma unroll
    for (int rj = 0; rj < 8; ++rj) {
      float s;
      s = fmaf(-2.f, acc[rj][0], e2a.x);
      if (s < best[rj]) { best[rj] = s; bk[rj] = lane * 4 + 0; }
      s = fmaf(-2.f, acc[rj][1], e2a.y);
      if (s < best[rj]) { best[rj] = s; bk[rj] = lane * 4 + 1; }
      s = fmaf(-2.f, acc[rj][2], e2a.z);
      if (s < best[rj]) { best[rj] = s; bk[rj] = lane * 4 + 2; }
      s = fmaf(-2.f, acc[rj][3], e2a.w);
      if (s < best[rj]) { best[rj] = s; bk[rj] = lane * 4 + 3; }
      s = fmaf(-2.f, acc[rj][4], e2b.x);
      if (s < best[rj]) { best[rj] = s; bk[rj] = 256 + lane * 4 + 0; }
      s = fmaf(-2.f, acc[rj][5], e2b.y);
      if (s < best[rj]) { best[rj] = s; bk[rj] = 256 + lane * 4 + 1; }
      s = fmaf(-2.f, acc[rj][6], e2b.z);
      if (s < best[rj]) { best[rj] = s; bk[rj] = 256 + lane * 4 + 2; }
      s = fmaf(-2.f, acc[rj][7], e2b.w);
      if (s < best[rj]) { best[rj] = s; bk[rj] = 256 + lane * 4 + 3; }
    }

    // cross-lane first-min argmin
#pragma unroll
    for (int rj = 0; rj < 8; ++rj) {
      float bv = best[rj];
      int bi = bk[rj];
#pragma unroll
      for (int m = 1; m < 64; m <<= 1) {
        const float ov = __shfl_xor(bv, m, 64);
        const int ok = __shfl_xor(bi, m, 64);
        if (ov < bv || (ov == bv && ok < bi)) {
          bv = ov;
          bi = ok;
        }
      }
      bk[rj] = bi;
    }

    // gather + straight-through update (resL in xs[r][128+..], mq in xs[r][192+..])
#pragma unroll
    for (int rj = 0; rj < 8; ++rj) {
      const int r = wv * 8 + rj;
      const float q = etg[((long)((l << 9) + bk[rj])) * 64 + lane];
      const float res = xs[r][128 + lane];
      const float t = q - res;
      const float qst = res + t;
      dloc = fmaf(t, t, dloc);
      xs[r][128 + lane] = res - qst;
      if (l == 0) xs[r][192 + lane] = qst;
    }
  }

#pragma unroll
  for (int m = 1; m < 64; m <<= 1) dloc += __shfl_xor(dloc, m, 64);
  if (lane == 0) atomicAdd(dsum, dloc);

  // ---- dec1 tail: buf[r][o] = sum_d mq[r][d] * wTd1[d][o] + d1b[o] (no relu) ----
  {
    float acc1[8][4];
#pragma unroll
    for (int i = 0; i < 8; ++i)
#pragma unroll
      for (int j = 0; j < 4; ++j) acc1[i][j] = 0.f;

    const float* w1base = wTd1 + lane * 4;
#pragma unroll 2
    for (int d = 0; d < 64; d += 2) {
      const float4 wA = *(const float4*)(w1base + (d + 0) * 256);
      const float4 wB = *(const float4*)(w1base + (d + 1) * 256);
#pragma unroll
      for (int rj = 0; rj < 8; ++rj) {
        const int r = wv * 8 + rj;
        const float xA = xs[r][192 + d];
        const float xB = xs[r][192 + d + 1];
        acc1[rj][0] = fmaf(xA, wA.x, acc1[rj][0]);
        acc1[rj][1] = fmaf(xA, wA.y, acc1[rj][1]);
        acc1[rj][2] = fmaf(xA, wA.z, acc1[rj][2]);
        acc1[rj][3] = fmaf(xA, wA.w, acc1[rj][3]);
        acc1[rj][0] = fmaf(xB, wB.x, acc1[rj][0]);
        acc1[rj][1] = fmaf(xB, wB.y, acc1[rj][1]);
        acc1[rj][2] = fmaf(xB, wB.z, acc1[rj][2]);
        acc1[rj][3] = fmaf(xB, wB.w, acc1[rj][3]);
      }
    }
    const float4 bv = *(const float4*)(d1b + lane * 4);
#pragma unroll
    for (int rj = 0; rj < 8; ++rj) {
      float4 v;
      v.x = acc1[rj][0] + bv.x;
      v.y = acc1[rj][1] + bv.y;
      v.z = acc1[rj][2] + bv.z;
      v.w = acc1[rj][3] + bv.w;
      *(float4*)(buf + (row0 + wv * 8 + rj) * (long)SB + lane * 4) = v;
    }
  }
}

// ---------------- FUSED decoder tail: d2 (256->128, relu both) + d3 (128->165) --------
__global__ __launch_bounds__(256, 3) void dec23_k(const float* __restrict__ in,
                                                  const float* __restrict__ wTd2,
                                                  const float* __restrict__ b2,
                                                  const float* __restrict__ wTd3,
                                                  const float* __restrict__ b3,
                                                  float* __restrict__ out) {
  __shared__ float xs[32][256];
  __shared__ float ts[32][132];
  const int tid = threadIdx.x, lane = tid & 63, wv = tid >> 6;
  const long row0 = (long)blockIdx.x * 32;

  for (int i = tid; i < 32 * 256; i += 256) {
    const int r = i >> 8, c = i & 255;
    xs[r][c] = frelu(in[(row0 + r) * (long)SB + c]);
  }
  __syncthreads();

  // phase 1: t[r][o] = relu(sum_k x[r][k] * wTd2[k][o] + b2[o]), o = lane*2..+1
  {
    float a2[8][2];
#pragma unroll
    for (int i = 0; i < 8; ++i) {
      a2[i][0] = 0.f;
      a2[i][1] = 0.f;
    }
    const float* w2base = wTd2 + lane * 2;
#pragma unroll 2
    for (int k0 = 0; k0 < 256; k0 += 4) {
      const float2 w0 = *(const float2*)(w2base + (k0 + 0) * 128);
      const float2 w1 = *(const float2*)(w2base + (k0 + 1) * 128);
      const float2 w2v = *(const float2*)(w2base + (k0 + 2) * 128);
      const float2 w3 = *(const float2*)(w2base + (k0 + 3) * 128);
#pragma unroll
      for (int rj = 0; rj < 8; ++rj) {
        const float4 x = *(const float4*)(&xs[wv * 8 + rj][k0]);
        a2[rj][0] = fmaf(x.x, w0.x, a2[rj][0]);
        a2[rj][1] = fmaf(x.x, w0.y, a2[rj][1]);
        a2[rj][0] = fmaf(x.y, w1.x, a2[rj][0]);
        a2[rj][1] = fmaf(x.y, w1.y, a2[rj][1]);
        a2[rj][0] = fmaf(x.z, w2v.x, a2[rj][0]);
        a2[rj][1] = fmaf(x.z, w2v.y, a2[rj][1]);
        a2[rj][0] = fmaf(x.w, w3.x, a2[rj][0]);
        a2[rj][1] = fmaf(x.w, w3.y, a2[rj][1]);
      }
    }
    const float b20 = b2[lane * 2 + 0];
    const float b21 = b2[lane * 2 + 1];
#pragma unroll
    for (int rj = 0; rj < 8; ++rj) {
      const int r = wv * 8 + rj;
      ts[r][lane * 2 + 0] = frelu(a2[rj][0] + b20);
      ts[r][lane * 2 + 1] = frelu(a2[rj][1] + b21);
    }
  }
  // ts rows are wave-private: no barrier needed

  // phase 2: out[r][o] = sum_k t[r][k] * wTd3[k][o] + b3[o], o = lane*4..+3 (<165)
  {
    float a3[8][4];
#pragma unroll
    for (int i = 0; i < 8; ++i)
#pragma unroll
      for (int j = 0; j < 4; ++j) a3[i][j] = 0.f;

    const float* w3base = wTd3 + lane * 4;
#pragma unroll 2
    for (int k0 = 0; k0 < 128; k0 += 4) {
      const float4 wk0 = *(const float4*)(w3base + (k0 + 0) * 256);
      const float4 wk1 = *(const float4*)(w3base + (k0 + 1) * 256);
      const float4 wk2 = *(const float4*)(w3base + (k0 + 2) * 256);
      const float4 wk3 = *(const float4*)(w3base + (k0 + 3) * 256);
#pragma unroll
      for (int rj = 0; rj < 8; ++rj) {
        const float4 t4 = *(const float4*)(&ts[wv * 8 + rj][k0]);
        a3[rj][0] = fmaf(t4.x, wk0.x, a3[rj][0]);
        a3[rj][1] = fmaf(t4.x, wk0.y, a3[rj][1]);
        a3[rj][2] = fmaf(t4.x, wk0.z, a3[rj][2]);
        a3[rj][3] = fmaf(t4.x, wk0.w, a3[rj][3]);
        a3[rj][0] = fmaf(t4.y, wk1.x, a3[rj][0]);
        a3[rj][1] = fmaf(t4.y, wk1.y, a3[rj][1]);
        a3[rj][2] = fmaf(t4.y, wk1.z, a3[rj][2]);
        a3[rj][3] = fmaf(t4.y, wk1.w, a3[rj][3]);
        a3[rj][0] = fmaf(t4.z, wk2.x, a3[rj][0]);
        a3[rj][1] = fmaf(t4.z, wk2.y, a3[rj][1]);
        a3[rj][2] = fmaf(t4.z, wk2.z, a3[rj][2]);
        a3[rj][3] = fmaf(t4.z, wk2.w, a3[rj][3]);
        a3[rj][0] = fmaf(t4.w, wk3.x, a3[rj][0]);
        a3[rj][1] = fmaf(t4.w, wk3.y, a3[rj][1]);
        a3[rj][2] = fmaf(t4.w, wk3.z, a3[rj][2]);
        a3[rj][3] = fmaf(t4.w, wk3.w, a3[rj][3]);
      }
    }
    float bias[4];
#pragma unroll
    for (int j = 0; j < 4; ++j) {
      const int o = lane * 4 + j;
      bias[j] = (o < 165) ? b3[o] : 0.f;
    }
#pragma unroll
    for (int rj = 0; rj < 8; ++rj) {
      const long rbase = (row0 + wv * 8 + rj) * 165L;
#pragma unroll
      for (int j = 0; j < 4; ++j) {
        const int o = lane * 4 + j;
        if (o < 165) out[rbase + o] = a3[rj][j] + bias[j];
      }
    }
  }
}

__global__ void finalize_k(const float* __restrict__ dsum, float* __restrict__ out) {
  if (threadIdx.x == 0 && blockIdx.x == 0)
    out[0] = *dsum * (1.0f / (4.0f * 65536.0f * 64.0f));
}

// ---------------- launch ----------------
extern "C" void kernel_launch(void* const* d_in, const int* in_sizes, int n_in, void* d_out,
                              int out_size, void* d_ws, size_t ws_size, hipStream_t stream) {
  (void)in_sizes; (void)n_in; (void)out_size; (void)ws_size;
  const float* x = (const float*)d_in[0];
  const float* enc_w1 = (const float*)d_in[1];
  const float* enc_b1 = (const float*)d_in[2];
  const float* enc_w2 = (const float*)d_in[3];
  const float* enc_b2 = (const float*)d_in[4];
  const float* enc_w3 = (const float*)d_in[5];
  const float* enc_b3 = (const float*)d_in[6];
  const float* enc_res_wa = (const float*)d_in[7];
  const float* enc_res_ba = (const float*)d_in[8];
  const float* enc_res_wb = (const float*)d_in[9];
  const float* enc_res_bb = (const float*)d_in[10];
  const float* q_w = (const float*)d_in[11];
  const float* q_b = (const float*)d_in[12];
  const float* embeds = (const float*)d_in[13];
  const float* dec_w1 = (const float*)d_in[14];
  const float* dec_b1 = (const float*)d_in[15];
  const float* dec_res_wa = (const float*)d_in[16];
  const float* dec_res_ba = (const float*)d_in[17];
  const float* dec_res_wb = (const float*)d_in[18];
  const float* dec_res_bb = (const float*)d_in[19];
  const float* dec_w2 = (const float*)d_in[20];
  const float* dec_b2 = (const float*)d_in[21];
  const float* dec_w3 = (const float*)d_in[22];
  const float* dec_b3 = (const float*)d_in[23];

  float* ws = (float*)d_ws;
  float* buf = ws;                          // [N][256]
  float* W = ws + (long)NROWS * SB;         // weight/codebook region

  float* dout = (float*)d_out;

  prep_k<<<(PREP_N + 255) / 256, 256, 0, stream>>>(enc_w1, enc_w2, enc_w3, q_w, dec_w1, dec_w2,
                                                   dec_w3, enc_res_wa, enc_res_wb, dec_res_wa,
                                                   dec_res_wb, embeds, W);

  const int GB = NROWS / 32;   // 2048 blocks (conv2, vq_fused, dec23)
  const int GR = NROWS / 64;   // 1024 blocks (conv6, resblock pairs)

  // encoder
  conv2_k<165, 168, 128, 2, 165, SB, false, true><<<GB, 256, 0, stream>>>(x, W + OFF_WT1, enc_b1, buf);
  conv6_k<128, 256, 256, SB, SB, false, true><<<GR, 512, 0, stream>>>(buf, W + OFF_WT2, enc_b2, buf);
  conv6_k<256, 256, 256, SB, SB, false, false><<<GR, 512, 0, stream>>>(buf, W + OFF_WT3, enc_b3, buf);
  resblock_pair_k<<<GR, 512, 0, stream>>>(buf, W + OFF_WAPE, enc_res_ba, W + OFF_WBTE, enc_res_bb);

  // q-conv + residual VQ + dec1 (fused)
  vq_fused_k<<<GB, 256, 0, stream>>>(buf, W + OFF_WTQ, q_b, embeds, W + OFF_EN2, W + OFF_ETG,
                                     W + OFF_DSUM, W + OFF_WTD1, dec_b1);

  // decoder
  resblock_pair_k<<<GR, 512, 0, stream>>>(buf, W + OFF_WAPD, dec_res_ba, W + OFF_WBTD, dec_res_bb);
  dec23_k<<<GB, 256, 0, stream>>>(buf, W + OFF_WTD2, dec_b2, W + OFF_WTD3, dec_b3, dout);

  finalize_k<<<1, 64, 0, stream>>>(W + OFF_DSUM, dout + (long)NROWS * 165);
}